// Round 10
// baseline (2025.014 us; speedup 1.0000x reference)
//
#include <hip/hip_runtime.h>
#include <math.h>

// Problem dims
#define NN   2048      // nodes
#define BB   64        // batch
#define FF   48        // in features
#define EE   65536     // edges per graph
#define CC   7         // out channels
#define HH   20        // hidden

// ---- ws layout (bytes), ws_size = 256 MiB ----
#define OFF_DEG      0u
#define OFF_CURSOR   32768u
#define ZBYTES       65536u
#define OFF_DINV     65536u            // float[4][N]
#define OFF_ROWPTR   98304u            // int[4][N+1]
#define OFF_CSRC     131584u           // int[4][E]
#define OFF_CSRW     1180160u          // float[4][E]
#define OFF_H1       2228736u          // 6 x bf16[N][20][B] (u16) = 6 x 5.24MB
#define OFF_P        OFF_H1            // 6 x float[N][7][B], overlays H1 (dead at spmm2)
#define OFF_Y        65143296u         // 6 x float[N][20][B]; init = xV+b, then act in place
#define OFF_H2       128057856u        // 6 x bf16[N][8][B] (u16, padded to 8 ch) = 6 x 2MB
#define OFF_YV       153223680u        // 6 x float[N][7][B]
#define OFF_T        175243776u        // float[N][40][B] 21MB
// end = 196,215,296 B < 256 MiB

#define H1S  2621440u   // elements per branch in H1(u16) / Y(f32)
#define H2S  1048576u   // u16 elements per branch in H2 (padded)
#define YVS  917504u    // floats per branch in YV / P

__device__ __forceinline__ unsigned short bf16_rne(float x) {
    unsigned u = __float_as_uint(x);
    u += 0x7fffu + ((u >> 16) & 1u);
    return (unsigned short)(u >> 16);
}
__device__ __forceinline__ float4 ubf4(uint2 u) {
    float4 r;
    r.x = __uint_as_float(u.x << 16);
    r.y = __uint_as_float(u.x & 0xffff0000u);
    r.z = __uint_as_float(u.y << 16);
    r.w = __uint_as_float(u.y & 0xffff0000u);
    return r;
}

// ---------------- CSR build ----------------
__global__ __launch_bounds__(256) void count_deg_kernel(
    const int* __restrict__ c0, const int* __restrict__ c1,
    const int* __restrict__ c2, const int* __restrict__ c3, int* __restrict__ deg)
{
    int idx = blockIdx.x * 256 + threadIdx.x;          // 4*E threads
    int g = idx >> 16, e = idx & 0xFFFF;
    const int* cp = g == 0 ? c0 : g == 1 ? c1 : g == 2 ? c2 : c3;
    atomicAdd(&deg[(g << 11) + cp[e]], 1);
}

__global__ __launch_bounds__(256) void scan_dinv_kernel(
    const int* __restrict__ deg, int* __restrict__ rowptr, float* __restrict__ dinv)
{
    int g = blockIdx.x, t = threadIdx.x;
    __shared__ int part[256];
    const int* d = deg + g * NN;
    int loc[8]; int s = 0;
#pragma unroll
    for (int j = 0; j < 8; ++j) { loc[j] = d[t * 8 + j]; s += loc[j]; }
    part[t] = s; __syncthreads();
    for (int off = 1; off < 256; off <<= 1) {
        int v = (t >= off) ? part[t - off] : 0;
        __syncthreads();
        part[t] += v;
        __syncthreads();
    }
    int run = (t > 0) ? part[t - 1] : 0;
    int* rp = rowptr + g * (NN + 1);
#pragma unroll
    for (int j = 0; j < 8; ++j) {
        int n = t * 8 + j;
        rp[n] = run; run += loc[j];
        dinv[g * NN + n] = loc[j] > 0 ? 1.0f / sqrtf((float)loc[j]) : 0.0f;
    }
    if (t == 255) rp[NN] = run;
}

__global__ __launch_bounds__(256) void fill_csr_kernel(
    const int* __restrict__ r0, const int* __restrict__ c0,
    const int* __restrict__ r1, const int* __restrict__ c1,
    const int* __restrict__ r2, const int* __restrict__ c2,
    const int* __restrict__ r3, const int* __restrict__ c3,
    const int* __restrict__ rowptr, int* __restrict__ cursor,
    const float* __restrict__ dinv, int* __restrict__ csrc, float* __restrict__ cw)
{
    int idx = blockIdx.x * 256 + threadIdx.x;
    int g = idx >> 16, e = idx & 0xFFFF;
    const int* rp = g == 0 ? r0 : g == 1 ? r1 : g == 2 ? r2 : r3;
    const int* cp = g == 0 ? c0 : g == 1 ? c1 : g == 2 ? c2 : c3;
    int r = rp[e], c = cp[e];
    int pos = atomicAdd(&cursor[(g << 11) + c], 1);
    int o = rowptr[g * (NN + 1) + c] + pos;
    csrc[(g << 16) + o] = r;
    cw[(g << 16) + o] = dinv[(g << 11) + r] * dinv[(g << 11) + c];
}

// ---------------- unified dual GEMM (7 branches): [M,48]@[48,20] x2 ----------------
// 512-row tile, 512 thr = 256 row-slots x 2 k-halves; thread owns rows (r, r+256).
// Weights staged in LDS [half][f][A:10|pad2|B:10|pad2] -> wave-uniform ds_read
// broadcasts into VGPRs (no SGPR-pressure SMEM pipeline, no conflicts).
// X staged per 24-col phase at stride 28 (28r mod 32 covers all 8 bank groups ->
// ideal-rate ds_read_b128). br<6: out H1(bf16)+Y(f32); br==6: out T (o_lt linear).
__global__ __launch_bounds__(512, 2) void gemm48_all(
    const float* __restrict__ X0, const float* __restrict__ X1,
    const float* __restrict__ X2, const float* __restrict__ X3,
    const float* __restrict__ X4, const float* __restrict__ X5,
    const float* __restrict__ W1, const float* __restrict__ V1,
    const float* __restrict__ b1,
    const float* __restrict__ Wlt, const float* __restrict__ blt,
    unsigned short* __restrict__ H1u, float* __restrict__ Y, float* __restrict__ T)
{
    int br = blockIdx.y;
    const float* X = br == 0 ? X0 : br == 1 ? X1 : br == 2 ? X2 :
                     br == 3 ? X3 : br == 4 ? X4 : X5;

    __shared__ float xs[512 * 28];          // 57344 B
    __shared__ float wls[2 * 48 * 24];      // 9216 B: [half][f][0..9=A,12..21=B]
    int t = threadIdx.x;
    const float4* Xv = reinterpret_cast<const float4*>(X) + (size_t)blockIdx.x * 6144;

    // stage weights (once)
    if (br < 6) {
        const float* Wa = W1 + br * 960;
        const float* Wb = V1 + br * 960;
        for (int i = t; i < 2304; i += 512) {
            int j24 = i % 24, f = (i / 24) % 48, h = i / 1152;
            int m = j24 / 12, j = j24 % 12;
            float v = 0.0f;
            if (j < 10) {
                int k = h * 10 + j;
                v = m == 0 ? Wa[f * 20 + k] : Wb[f * 20 + k];
            }
            wls[i] = v;
        }
    } else {
        for (int i = t; i < 2304; i += 512) {
            int j24 = i % 24, f = (i / 24) % 48, h = i / 1152;
            int m = j24 / 12, j = j24 % 12;
            float v = 0.0f;
            if (j < 10) {
                int k = h * 10 + j;
                v = m == 0 ? Wlt[f * 40 + k] : Wlt[f * 40 + 20 + k];
            }
            wls[i] = v;
        }
    }

    int r = t & 255;
    int h = t >> 8;              // k-half
    int kb = h * 10;

    float accA[2][10], accB[2][10];
#pragma unroll
    for (int j = 0; j < 10; ++j) {
        float ba, bv;
        if (br < 6) { ba = 0.0f; bv = b1[br * 20 + kb + j]; }
        else        { ba = blt[kb + j]; bv = blt[20 + kb + j]; }
        accA[0][j] = ba; accA[1][j] = ba;
        accB[0][j] = bv; accB[1][j] = bv;
    }

#pragma unroll
    for (int ph = 0; ph < 2; ++ph) {
        if (ph) __syncthreads();
#pragma unroll
        for (int i = 0; i < 6; ++i) {
            int fl4 = i * 512 + t;
            int rr = fl4 / 6, fq = fl4 - rr * 6;
            float4 v = Xv[rr * 12 + ph * 6 + fq];
            *reinterpret_cast<float4*>(&xs[rr * 28 + fq * 4]) = v;
        }
        __syncthreads();
#pragma unroll
        for (int fq = 0; fq < 6; ++fq) {
            float4 xA = *reinterpret_cast<const float4*>(&xs[r * 28 + fq * 4]);
            float4 xB = *reinterpret_cast<const float4*>(&xs[(r + 256) * 28 + fq * 4]);
#pragma unroll
            for (int ff = 0; ff < 4; ++ff) {
                int f = ph * 24 + fq * 4 + ff;
                const float* wp = &wls[(h * 48 + f) * 24];   // wave-uniform -> broadcast
                float4 wa0 = *reinterpret_cast<const float4*>(&wp[0]);
                float4 wa1 = *reinterpret_cast<const float4*>(&wp[4]);
                float2 wa2 = *reinterpret_cast<const float2*>(&wp[8]);
                float4 wb0 = *reinterpret_cast<const float4*>(&wp[12]);
                float4 wb1 = *reinterpret_cast<const float4*>(&wp[16]);
                float2 wb2 = *reinterpret_cast<const float2*>(&wp[20]);
                float a0 = ff == 0 ? xA.x : ff == 1 ? xA.y : ff == 2 ? xA.z : xA.w;
                float a1 = ff == 0 ? xB.x : ff == 1 ? xB.y : ff == 2 ? xB.z : xB.w;
#pragma unroll
                for (int rr = 0; rr < 2; ++rr) {
                    float a = rr == 0 ? a0 : a1;
                    accA[rr][0] += wa0.x * a; accA[rr][1] += wa0.y * a;
                    accA[rr][2] += wa0.z * a; accA[rr][3] += wa0.w * a;
                    accA[rr][4] += wa1.x * a; accA[rr][5] += wa1.y * a;
                    accA[rr][6] += wa1.z * a; accA[rr][7] += wa1.w * a;
                    accA[rr][8] += wa2.x * a; accA[rr][9] += wa2.y * a;
                    accB[rr][0] += wb0.x * a; accB[rr][1] += wb0.y * a;
                    accB[rr][2] += wb0.z * a; accB[rr][3] += wb0.w * a;
                    accB[rr][4] += wb1.x * a; accB[rr][5] += wb1.y * a;
                    accB[rr][6] += wb1.z * a; accB[rr][7] += wb1.w * a;
                    accB[rr][8] += wb2.x * a; accB[rr][9] += wb2.y * a;
                }
            }
        }
    }

    int n0 = blockIdx.x * 8;
#pragma unroll
    for (int rr = 0; rr < 2; ++rr) {
        int row = r + rr * 256;
        int n = n0 + (row >> 6), b = row & 63;
        if (br < 6) {
            size_t base = (size_t)br * H1S + (size_t)n * 1280 + (size_t)kb * 64 + b;
#pragma unroll
            for (int j = 0; j < 10; ++j) {
                H1u[base + (size_t)j * 64] = bf16_rne(accA[rr][j]);
                Y[base + (size_t)j * 64] = accB[rr][j];
            }
        } else {
            size_t base = (size_t)n * 2560 + b;
#pragma unroll
            for (int j = 0; j < 10; ++j) {
                T[base + (size_t)(kb + j) * 64] = accA[rr][j];
                T[base + (size_t)(20 + kb + j) * 64] = accB[rr][j];
            }
        }
    }
}

__device__ __forceinline__ void fma4(float4& a, float w, const float4 v) {
    a.x += w * v.x; a.y += w * v.y; a.z += w * v.z; a.w += w * v.w;
}
__device__ __forceinline__ float gelu_elu(float v) {
    float g = 0.5f * v * (1.0f + erff(v * 0.70710678118654752f));   // exact GELU
    return g > 0.0f ? g : expm1f(g);                                 // ELU
}

// ---------------- batched SpMM1 + GELU + ELU, bf16 gather, in-place on Y ----------------
// XCD-pinned slices; scalarized CSR; 8-deep gather of uint2 (4 bf16).
__global__ __launch_bounds__(256) void spmm1_all(
    const uint2* __restrict__ H1u, float4* __restrict__ Y,
    const int* __restrict__ rowptr, const int* __restrict__ csrc, const float* __restrict__ csrw)
{
    int bid = blockIdx.x;
    int w0 = (bid & 7) * 1920 + (bid >> 3);   // 0..15359
    int sl = w0 >> 9;                          // 0..29
    int ng = w0 & 511;
    int br = sl / 5, q = sl - br * 5;

    int gg = br == 1 ? 1 : br == 2 ? 2 : br == 5 ? 3 : 0;
    const int*   rp  = rowptr + gg * (NN + 1);
    const int*   src = csrc + (size_t)gg * EE;
    const float* wts = csrw + (size_t)gg * EE;
    const uint2* h = H1u + (size_t)br * (H1S / 4);   // 320 uint2 per node-row
    float4*      y = Y + (size_t)br * (H1S / 4);     // 320 float4 per node-row

    int wv = __builtin_amdgcn_readfirstlane(threadIdx.x >> 6);
    int lane = threadIdx.x & 63;
    int n = ng * 4 + wv;                       // wave-uniform -> scalar CSR loads
    int off = q * 64 + lane;
    int s0 = rp[n], s1 = rp[n + 1];

    float4 a0 = {0,0,0,0}, a1 = {0,0,0,0}, a2 = {0,0,0,0}, a3 = {0,0,0,0};
    int e = s0;
    for (; e + 8 <= s1; e += 8) {
        int   iA = src[e],   iB = src[e+1], iC = src[e+2], iD = src[e+3];
        int   iE = src[e+4], iF = src[e+5], iG = src[e+6], iH = src[e+7];
        float wA = wts[e],   wB = wts[e+1], wC = wts[e+2], wD = wts[e+3];
        float wE = wts[e+4], wF = wts[e+5], wG = wts[e+6], wH = wts[e+7];
        uint2 u0 = h[iA * 320 + off];
        uint2 u1 = h[iB * 320 + off];
        uint2 u2 = h[iC * 320 + off];
        uint2 u3 = h[iD * 320 + off];
        uint2 u4 = h[iE * 320 + off];
        uint2 u5 = h[iF * 320 + off];
        uint2 u6 = h[iG * 320 + off];
        uint2 u7 = h[iH * 320 + off];
        fma4(a0, wA, ubf4(u0)); fma4(a1, wB, ubf4(u1));
        fma4(a2, wC, ubf4(u2)); fma4(a3, wD, ubf4(u3));
        fma4(a0, wE, ubf4(u4)); fma4(a1, wF, ubf4(u5));
        fma4(a2, wG, ubf4(u6)); fma4(a3, wH, ubf4(u7));
    }
    for (; e + 2 <= s1; e += 2) {
        uint2 u0 = h[src[e] * 320 + off];
        uint2 u1 = h[src[e+1] * 320 + off];
        fma4(a0, wts[e], ubf4(u0)); fma4(a1, wts[e+1], ubf4(u1));
    }
    if (e < s1) fma4(a0, wts[e], ubf4(h[src[e] * 320 + off]));
    a0.x += a1.x + a2.x + a3.x;
    a0.y += a1.y + a2.y + a3.y;
    a0.z += a1.z + a2.z + a3.z;
    a0.w += a1.w + a2.w + a3.w;

    size_t b0 = (size_t)n * 320 + off;
    float4 xv = y[b0];
    float4 r;
    r.x = gelu_elu(a0.x + xv.x);
    r.y = gelu_elu(a0.y + xv.y);
    r.z = gelu_elu(a0.z + xv.z);
    r.w = gelu_elu(a0.w + xv.w);
    y[b0] = r;
}

// ---------------- batched dual GEMM2: [M,20]@[20,7] x2; H2 bf16, padded to 8 ch ----------------
__global__ __launch_bounds__(256) void gemm2_all(
    const float* __restrict__ Y, const float* __restrict__ W2,
    const float* __restrict__ V2, const float* __restrict__ b2,
    unsigned short* __restrict__ H2u, float* __restrict__ YV)
{
    int br = blockIdx.y;
    const float* y  = Y + (size_t)br * H1S;
    unsigned short* h2 = H2u + (size_t)br * H2S;
    float* yv = YV + (size_t)br * YVS;
    __shared__ float w2s[140], v2s[140], b2s[7];
    int t = threadIdx.x;
    if (t < 140) { w2s[t] = W2[br * 140 + t]; v2s[t] = V2[br * 140 + t]; }
    if (t < 7) b2s[t] = b2[br * 7 + t];
    __syncthreads();
    int wv = __builtin_amdgcn_readfirstlane(t >> 6), b = t & 63;
    int n = blockIdx.x * 4 + wv;
    size_t yb = (size_t)n * 1280 + b;
    float yr[20];
#pragma unroll
    for (int k = 0; k < 20; ++k) yr[k] = y[yb + (size_t)k * 64];
    float a[7] = {}, v[7] = {};
#pragma unroll
    for (int k = 0; k < 20; ++k) {
        float yk = yr[k];
#pragma unroll
        for (int c = 0; c < 7; ++c) {
            a[c] += yk * w2s[k * 7 + c];
            v[c] += yk * v2s[k * 7 + c];
        }
    }
    size_t hb = (size_t)n * 512 + b;
#pragma unroll
    for (int c = 0; c < 7; ++c) h2[hb + (size_t)c * 64] = bf16_rne(a[c]);
    h2[hb + 7 * 64] = 0;                          // padding channel
    size_t vb = (size_t)n * 448 + b;
#pragma unroll
    for (int c = 0; c < 7; ++c) yv[vb + (size_t)c * 64] = v[c] + b2s[c];
}

// ---------------- batched SpMM2 + ReLU + softmax(B) -> per-branch P ----------------
// XCD-pinned; scalarized CSR; 8-deep bf16 gather. Row = [8 ch][64 b] u16 = 128 uint2.
__global__ __launch_bounds__(256) void spmm2_all(
    const uint2* __restrict__ H2u, const float* __restrict__ YV,
    const int* __restrict__ rowptr, const int* __restrict__ csrc, const float* __restrict__ csrw,
    float* __restrict__ P)
{
    int bid = blockIdx.x;
    int w0 = (bid & 7) * 768 + (bid >> 3);    // 0..6143
    int sl = w0 >> 9;                          // 0..11
    int ng = w0 & 511;
    int br = sl >> 1, hh = sl & 1;

    int gg = br == 1 ? 1 : br == 2 ? 2 : br == 5 ? 3 : 0;
    const int*   rp  = rowptr + gg * (NN + 1);
    const int*   src = csrc + (size_t)gg * EE;
    const float* wts = csrw + (size_t)gg * EE;
    const uint2* h2 = H2u + (size_t)br * (H2S / 4);   // 128 uint2 per node-row
    const float* yv = YV + (size_t)br * YVS;
    float* p = P + (size_t)br * YVS;

    int wv = __builtin_amdgcn_readfirstlane(threadIdx.x >> 6);
    int lane = threadIdx.x & 63;
    int n = ng * 4 + wv;
    int s = hh * 64 + lane;          // uint2 slot in the 128-slot row
    int c = s >> 4;                  // 0..7 (7 = padding)
    int bq = lane & 15;              // b quad
    int s0 = rp[n], s1 = rp[n + 1];

    float4 a0 = {0,0,0,0}, a1 = {0,0,0,0}, a2 = {0,0,0,0}, a3 = {0,0,0,0};
    int e = s0;
    for (; e + 8 <= s1; e += 8) {
        int   iA = src[e],   iB = src[e+1], iC = src[e+2], iD = src[e+3];
        int   iE = src[e+4], iF = src[e+5], iG = src[e+6], iH = src[e+7];
        float wA = wts[e],   wB = wts[e+1], wC = wts[e+2], wD = wts[e+3];
        float wE = wts[e+4], wF = wts[e+5], wG = wts[e+6], wH = wts[e+7];
        uint2 u0 = h2[iA * 128 + s];
        uint2 u1 = h2[iB * 128 + s];
        uint2 u2 = h2[iC * 128 + s];
        uint2 u3 = h2[iD * 128 + s];
        uint2 u4 = h2[iE * 128 + s];
        uint2 u5 = h2[iF * 128 + s];
        uint2 u6 = h2[iG * 128 + s];
        uint2 u7 = h2[iH * 128 + s];
        fma4(a0, wA, ubf4(u0)); fma4(a1, wB, ubf4(u1));
        fma4(a2, wC, ubf4(u2)); fma4(a3, wD, ubf4(u3));
        fma4(a0, wE, ubf4(u4)); fma4(a1, wF, ubf4(u5));
        fma4(a2, wG, ubf4(u6)); fma4(a3, wH, ubf4(u7));
    }
    for (; e < s1; ++e) fma4(a0, wts[e], ubf4(h2[src[e] * 128 + s]));
    a0.x += a1.x + a2.x + a3.x;
    a0.y += a1.y + a2.y + a3.y;
    a0.z += a1.z + a2.z + a3.z;
    a0.w += a1.w + a2.w + a3.w;

    float4 z = {0,0,0,0};
    if (c < 7) {
        float4 yvv = *reinterpret_cast<const float4*>(&yv[(size_t)n * 448 + c * 64 + bq * 4]);
        z.x = fmaxf(a0.x + yvv.x, 0.0f);
        z.y = fmaxf(a0.y + yvv.y, 0.0f);
        z.z = fmaxf(a0.z + yvv.z, 0.0f);
        z.w = fmaxf(a0.w + yvv.w, 0.0f);
    }
    float m = fmaxf(fmaxf(z.x, z.y), fmaxf(z.z, z.w));
#pragma unroll
    for (int o = 8; o > 0; o >>= 1) m = fmaxf(m, __shfl_xor(m, o, 64));
    float4 pz;
    pz.x = expf(z.x - m); pz.y = expf(z.y - m);
    pz.z = expf(z.z - m); pz.w = expf(z.w - m);
    float sm = pz.x + pz.y + pz.z + pz.w;
#pragma unroll
    for (int o = 8; o > 0; o >>= 1) sm += __shfl_xor(sm, o, 64);
    float inv = 1.0f / sm;
    if (c < 7) {
        float4 r = { pz.x * inv, pz.y * inv, pz.z * inv, pz.w * inv };
        *reinterpret_cast<float4*>(&p[(size_t)n * 448 + c * 64 + bq * 4]) = r;
    }
}

// ---------------- wave softmax over 64 lanes (batch axis) ----------------
__device__ __forceinline__ void wave_softmax7(float* z)
{
#pragma unroll
    for (int c = 0; c < 7; ++c) {
        float m = z[c];
#pragma unroll
        for (int o = 32; o > 0; o >>= 1) m = fmaxf(m, __shfl_xor(m, o, 64));
        float p = expf(z[c] - m);
        float s = p;
#pragma unroll
        for (int o = 32; o > 0; o >>= 1) s += __shfl_xor(s, o, 64);
        z[c] = p / s;
    }
}

// ---------------- final: o_lt tail, dense+gnn heads, output [N][C][B] ----------------
__global__ __launch_bounds__(256) void combine_kernel(
    const float* __restrict__ T, const float* __restrict__ P,
    const float* __restrict__ Wl2, const float* __restrict__ bl2,
    const float* __restrict__ Wd, const float* __restrict__ bd,
    const float* __restrict__ Wg, const float* __restrict__ bg,
    float* __restrict__ out)
{
    __shared__ float wl2s[280], bl2s[7], wds[49], bds[7], wgs[49], bgs[7];
    int t = threadIdx.x;
    for (int i = t; i < 280; i += 256) wl2s[i] = Wl2[i];
    if (t < 49) { wds[t] = Wd[t]; wgs[t] = Wg[t]; }
    if (t < 7) { bl2s[t] = bl2[t]; bds[t] = bd[t]; bgs[t] = bg[t]; }
    __syncthreads();

    int wv = t >> 6, b = t & 63;
    int n = blockIdx.x * 4 + wv;
    size_t rbase = (size_t)n * 2560 + b;   // T is [n][40][b]
    float tr[40];
#pragma unroll
    for (int j = 0; j < 40; ++j) tr[j] = T[rbase + (size_t)j * 64];

    float u[7];
#pragma unroll
    for (int c = 0; c < 7; ++c) u[c] = bl2s[c];
    for (int j = 0; j < 40; ++j) {
        float tv = tr[j];
#pragma unroll
        for (int c = 0; c < 7; ++c) u[c] += tv * wl2s[j * 7 + c];
    }
    wave_softmax7(u);   // o_lt

    size_t sbase = (size_t)n * 448 + b;
    float sd[7], sg[7];
#pragma unroll
    for (int c = 0; c < 7; ++c) {
        size_t o = sbase + (size_t)c * 64;
        sg[c] = P[o] + P[YVS + o] + P[2 * YVS + o] + P[3 * YVS + o] + P[4 * YVS + o];
        sd[c] = 2.0f * P[5 * YVS + o] + 2.0f * u[c];
    }
    float dv[7];
#pragma unroll
    for (int c = 0; c < 7; ++c) dv[c] = bds[c];
#pragma unroll
    for (int c2 = 0; c2 < 7; ++c2) {
        float s = sd[c2];
#pragma unroll
        for (int c = 0; c < 7; ++c) dv[c] += s * wds[c2 * 7 + c];
    }
    wave_softmax7(dv);  // out_dense

    float gv[7];
#pragma unroll
    for (int c = 0; c < 7; ++c) gv[c] = bgs[c];
#pragma unroll
    for (int c2 = 0; c2 < 7; ++c2) {
        float s = sg[c2];
#pragma unroll
        for (int c = 0; c < 7; ++c) gv[c] += s * wgs[c2 * 7 + c];
    }
    wave_softmax7(gv);  // out_gnn

    size_t ob = (size_t)n * 448 + b;
#pragma unroll
    for (int c = 0; c < 7; ++c) out[ob + (size_t)c * 64] = dv[c] + gv[c];
}

// ---------------- host ----------------
extern "C" void kernel_launch(void* const* d_in, const int* in_sizes, int n_in,
                              void* d_out, int out_size, void* d_ws, size_t ws_size,
                              hipStream_t stream)
{
    (void)in_sizes; (void)n_in; (void)out_size; (void)ws_size;
    const int* e0 = (const int*)d_in[0];
    const int* e1 = (const int*)d_in[1];
    const int* e2 = (const int*)d_in[2];
    const int* e3 = (const int*)d_in[3];
    const float* X0 = (const float*)d_in[4];
    const float* X1 = (const float*)d_in[5];
    const float* X2 = (const float*)d_in[6];
    const float* X3 = (const float*)d_in[7];
    const float* X4 = (const float*)d_in[8];
    const float* X5 = (const float*)d_in[9];
    const float* W1  = (const float*)d_in[10];
    const float* V1  = (const float*)d_in[11];
    const float* b1  = (const float*)d_in[12];
    const float* W2  = (const float*)d_in[13];
    const float* V2  = (const float*)d_in[14];
    const float* b2  = (const float*)d_in[15];
    const float* Wlt = (const float*)d_in[16];
    const float* blt = (const float*)d_in[17];
    const float* Wl2 = (const float*)d_in[18];
    const float* bl2 = (const float*)d_in[19];
    const float* Wd  = (const float*)d_in[20];
    const float* bd  = (const float*)d_in[21];
    const float* Wg  = (const float*)d_in[22];
    const float* bg  = (const float*)d_in[23];

    char* ws = (char*)d_ws;
    int*   deg    = (int*)(ws + OFF_DEG);
    int*   cursor = (int*)(ws + OFF_CURSOR);
    float* dinv   = (float*)(ws + OFF_DINV);
    int*   rowptr = (int*)(ws + OFF_ROWPTR);
    int*   csrc   = (int*)(ws + OFF_CSRC);
    float* csrw   = (float*)(ws + OFF_CSRW);
    unsigned short* H1u = (unsigned short*)(ws + OFF_H1);
    float* Pbuf   = (float*)(ws + OFF_P);
    float* Y      = (float*)(ws + OFF_Y);
    unsigned short* H2u = (unsigned short*)(ws + OFF_H2);
    float* YV     = (float*)(ws + OFF_YV);
    float* Tbuf   = (float*)(ws + OFF_T);

    hipMemsetAsync(d_ws, 0, ZBYTES, stream);

    count_deg_kernel<<<1024, 256, 0, stream>>>(e0 + EE, e1 + EE, e2 + EE, e3 + EE, deg);
    scan_dinv_kernel<<<4, 256, 0, stream>>>(deg, rowptr, dinv);
    fill_csr_kernel<<<1024, 256, 0, stream>>>(e0, e0 + EE, e1, e1 + EE, e2, e2 + EE,
                                              e3, e3 + EE, rowptr, cursor, dinv, csrc, csrw);

    gemm48_all<<<dim3(256, 7), 512, 0, stream>>>(X0, X1, X2, X3, X4, X5,
                                                 W1, V1, b1, Wlt, blt, H1u, Y, Tbuf);
    spmm1_all<<<15360, 256, 0, stream>>>((const uint2*)H1u, (float4*)Y,
                                         rowptr, csrc, csrw);
    gemm2_all<<<dim3(512, 6), 256, 0, stream>>>(Y, W2, V2, b2, H2u, YV);
    spmm2_all<<<6144, 256, 0, stream>>>((const uint2*)H2u, YV,
                                        rowptr, csrc, csrw, Pbuf);
    combine_kernel<<<512, 256, 0, stream>>>(Tbuf, Pbuf, Wl2, bl2, Wd, bd, Wg, bg,
                                            (float*)d_out);
}

// Round 11
// 289.715 us; speedup vs baseline: 6.9897x; 6.9897x over previous
//
#include <hip/hip_runtime.h>
#include <math.h>

// Problem dims
#define NN   2048      // nodes
#define BB   64        // batch
#define FF   48        // in features
#define EE   65536     // edges per graph
#define CC   7         // out channels
#define HH   20        // hidden

// ---- ws layout (bytes), ws_size = 256 MiB ----
#define OFF_DEG      0u
#define OFF_CURSOR   32768u
#define ZBYTES       65536u
#define OFF_DINV     65536u            // float[4][N]
#define OFF_ROWPTR   98304u            // int[4][N+1]
#define OFF_CSRC     131584u           // int[4][E]
#define OFF_CSRW     1180160u          // float[4][E]
#define OFF_H1       2228736u          // 6 x bf16[N][20][B] (u16) = 6 x 5.24MB
#define OFF_P        OFF_H1            // 6 x float[N][7][B], overlays H1 (dead at spmm2)
#define OFF_Y        65143296u         // 6 x float[N][20][B]; init = xV+b, then act in place
#define OFF_H2       128057856u        // 6 x bf16[N][8][B] (u16, padded to 8 ch) = 6 x 2MB
#define OFF_YV       153223680u        // 6 x float[N][7][B]
#define OFF_T        175243776u        // float[N][40][B] 21MB
// end = 196,215,296 B < 256 MiB

#define H1S  2621440u   // elements per branch in H1(u16) / Y(f32)
#define H2S  1048576u   // u16 elements per branch in H2 (padded)
#define YVS  917504u    // floats per branch in YV / P

__device__ __forceinline__ unsigned short bf16_rne(float x) {
    unsigned u = __float_as_uint(x);
    u += 0x7fffu + ((u >> 16) & 1u);
    return (unsigned short)(u >> 16);
}
__device__ __forceinline__ float4 ubf4(uint2 u) {
    float4 r;
    r.x = __uint_as_float(u.x << 16);
    r.y = __uint_as_float(u.x & 0xffff0000u);
    r.z = __uint_as_float(u.y << 16);
    r.w = __uint_as_float(u.y & 0xffff0000u);
    return r;
}

// ---------------- CSR build ----------------
__global__ __launch_bounds__(256) void count_deg_kernel(
    const int* __restrict__ c0, const int* __restrict__ c1,
    const int* __restrict__ c2, const int* __restrict__ c3, int* __restrict__ deg)
{
    int idx = blockIdx.x * 256 + threadIdx.x;          // 4*E threads
    int g = idx >> 16, e = idx & 0xFFFF;
    const int* cp = g == 0 ? c0 : g == 1 ? c1 : g == 2 ? c2 : c3;
    atomicAdd(&deg[(g << 11) + cp[e]], 1);
}

__global__ __launch_bounds__(256) void scan_dinv_kernel(
    const int* __restrict__ deg, int* __restrict__ rowptr, float* __restrict__ dinv)
{
    int g = blockIdx.x, t = threadIdx.x;
    __shared__ int part[256];
    const int* d = deg + g * NN;
    int loc[8]; int s = 0;
#pragma unroll
    for (int j = 0; j < 8; ++j) { loc[j] = d[t * 8 + j]; s += loc[j]; }
    part[t] = s; __syncthreads();
    for (int off = 1; off < 256; off <<= 1) {
        int v = (t >= off) ? part[t - off] : 0;
        __syncthreads();
        part[t] += v;
        __syncthreads();
    }
    int run = (t > 0) ? part[t - 1] : 0;
    int* rp = rowptr + g * (NN + 1);
#pragma unroll
    for (int j = 0; j < 8; ++j) {
        int n = t * 8 + j;
        rp[n] = run; run += loc[j];
        dinv[g * NN + n] = loc[j] > 0 ? 1.0f / sqrtf((float)loc[j]) : 0.0f;
    }
    if (t == 255) rp[NN] = run;
}

__global__ __launch_bounds__(256) void fill_csr_kernel(
    const int* __restrict__ r0, const int* __restrict__ c0,
    const int* __restrict__ r1, const int* __restrict__ c1,
    const int* __restrict__ r2, const int* __restrict__ c2,
    const int* __restrict__ r3, const int* __restrict__ c3,
    const int* __restrict__ rowptr, int* __restrict__ cursor,
    const float* __restrict__ dinv, int* __restrict__ csrc, float* __restrict__ cw)
{
    int idx = blockIdx.x * 256 + threadIdx.x;
    int g = idx >> 16, e = idx & 0xFFFF;
    const int* rp = g == 0 ? r0 : g == 1 ? r1 : g == 2 ? r2 : r3;
    const int* cp = g == 0 ? c0 : g == 1 ? c1 : g == 2 ? c2 : c3;
    int r = rp[e], c = cp[e];
    int pos = atomicAdd(&cursor[(g << 11) + c], 1);
    int o = rowptr[g * (NN + 1) + c] + pos;
    csrc[(g << 16) + o] = r;
    cw[(g << 16) + o] = dinv[(g << 11) + r] * dinv[(g << 11) + c];
}

// ---------------- main dual GEMM (6 branches): [M,48]@[48,20] x2 ----------------
// r9-proven structure (104us, VGPR 40, no spill): 512-row tile, 512 thr =
// 256 row-slots x 2 k-halves; thread owns rows (r, r+256). Weights via
// wave-uniform s_loads with LITERAL stride 20 (imm-offset). X staged in two
// 24-col phases (LDS 48KB). Outputs H1 bf16 + Y f32.
__global__ __launch_bounds__(512, 4) void gemm48_main(
    const float* __restrict__ X0, const float* __restrict__ X1,
    const float* __restrict__ X2, const float* __restrict__ X3,
    const float* __restrict__ X4, const float* __restrict__ X5,
    const float* __restrict__ W1, const float* __restrict__ V1,
    const float* __restrict__ b1,
    unsigned short* __restrict__ H1u, float* __restrict__ Y)
{
    int br = blockIdx.y;
    const float* X = br == 0 ? X0 : br == 1 ? X1 : br == 2 ? X2 :
                     br == 3 ? X3 : br == 4 ? X4 : X5;
    const float* Wa = W1 + br * 960;
    const float* Wb = V1 + br * 960;
    const float* bb = b1 + br * 20;

    __shared__ float xs[512 * 24];
    int t = threadIdx.x;
    const float4* Xv = reinterpret_cast<const float4*>(X) + (size_t)blockIdx.x * 6144;

    int r = t & 255;
    int kb = __builtin_amdgcn_readfirstlane((t >> 8) * 10);
    const float* wap = Wa + kb;
    const float* wbp = Wb + kb;

    float accA[2][10], accB[2][10];
#pragma unroll
    for (int j = 0; j < 10; ++j) {
        float bv = bb[kb + j];
        accA[0][j] = 0.0f; accA[1][j] = 0.0f;
        accB[0][j] = bv;   accB[1][j] = bv;
    }

#pragma unroll
    for (int ph = 0; ph < 2; ++ph) {
        if (ph) __syncthreads();
#pragma unroll
        for (int i = 0; i < 6; ++i) {
            int fl4 = i * 512 + t;
            int rr = fl4 / 6, fq = fl4 - rr * 6;
            float4 v = Xv[rr * 12 + ph * 6 + fq];
            *reinterpret_cast<float4*>(&xs[fl4 * 4]) = v;   // addr == rr*24 + fq*4
        }
        __syncthreads();
#pragma unroll
        for (int fq = 0; fq < 6; ++fq) {
            float4 xA = *reinterpret_cast<const float4*>(&xs[r * 24 + fq * 4]);
            float4 xB = *reinterpret_cast<const float4*>(&xs[(r + 256) * 24 + fq * 4]);
#pragma unroll
            for (int ff = 0; ff < 4; ++ff) {
                int f = ph * 24 + fq * 4 + ff;
                float a0 = ff == 0 ? xA.x : ff == 1 ? xA.y : ff == 2 ? xA.z : xA.w;
                float a1 = ff == 0 ? xB.x : ff == 1 ? xB.y : ff == 2 ? xB.z : xB.w;
                const float* wr = wap + f * 20;   // literal stride -> imm-offset s_loads
                const float* vr = wbp + f * 20;
#pragma unroll
                for (int j = 0; j < 10; ++j) {
                    float w = wr[j], v2 = vr[j];
                    accA[0][j] += w * a0;  accA[1][j] += w * a1;
                    accB[0][j] += v2 * a0; accB[1][j] += v2 * a1;
                }
            }
        }
    }

    int n0 = blockIdx.x * 8;
#pragma unroll
    for (int rr = 0; rr < 2; ++rr) {
        int row = r + rr * 256;
        int n = n0 + (row >> 6), b = row & 63;
        size_t base = (size_t)br * H1S + (size_t)n * 1280 + (size_t)kb * 64 + b;
#pragma unroll
        for (int j = 0; j < 10; ++j) {
            H1u[base + (size_t)j * 64] = bf16_rne(accA[rr][j]);
            Y[base + (size_t)j * 64] = accB[rr][j];
        }
    }
}

// ---------------- o_lt GEMM: T = Xlt@Wlt + blt, literal stride 40 ----------------
__global__ __launch_bounds__(512, 4) void gemm48_lt(
    const float* __restrict__ X, const float* __restrict__ Wlt,
    const float* __restrict__ blt, float* __restrict__ T)
{
    __shared__ float xs[512 * 24];
    int t = threadIdx.x;
    const float4* Xv = reinterpret_cast<const float4*>(X) + (size_t)blockIdx.x * 6144;

    int r = t & 255;
    int kb = __builtin_amdgcn_readfirstlane((t >> 8) * 10);
    const float* wap = Wlt + kb;          // cols kb..kb+9
    const float* wbp = Wlt + 20 + kb;     // cols 20+kb..20+kb+9

    float accA[2][10], accB[2][10];
#pragma unroll
    for (int j = 0; j < 10; ++j) {
        accA[0][j] = blt[kb + j];      accA[1][j] = accA[0][j];
        accB[0][j] = blt[20 + kb + j]; accB[1][j] = accB[0][j];
    }

#pragma unroll
    for (int ph = 0; ph < 2; ++ph) {
        if (ph) __syncthreads();
#pragma unroll
        for (int i = 0; i < 6; ++i) {
            int fl4 = i * 512 + t;
            int rr = fl4 / 6, fq = fl4 - rr * 6;
            float4 v = Xv[rr * 12 + ph * 6 + fq];
            *reinterpret_cast<float4*>(&xs[fl4 * 4]) = v;
        }
        __syncthreads();
#pragma unroll
        for (int fq = 0; fq < 6; ++fq) {
            float4 xA = *reinterpret_cast<const float4*>(&xs[r * 24 + fq * 4]);
            float4 xB = *reinterpret_cast<const float4*>(&xs[(r + 256) * 24 + fq * 4]);
#pragma unroll
            for (int ff = 0; ff < 4; ++ff) {
                int f = ph * 24 + fq * 4 + ff;
                float a0 = ff == 0 ? xA.x : ff == 1 ? xA.y : ff == 2 ? xA.z : xA.w;
                float a1 = ff == 0 ? xB.x : ff == 1 ? xB.y : ff == 2 ? xB.z : xB.w;
                const float* wr = wap + f * 40;
                const float* vr = wbp + f * 40;
#pragma unroll
                for (int j = 0; j < 10; ++j) {
                    float w = wr[j], v2 = vr[j];
                    accA[0][j] += w * a0;  accA[1][j] += w * a1;
                    accB[0][j] += v2 * a0; accB[1][j] += v2 * a1;
                }
            }
        }
    }

    int n0 = blockIdx.x * 8;
#pragma unroll
    for (int rr = 0; rr < 2; ++rr) {
        int row = r + rr * 256;
        int n = n0 + (row >> 6), b = row & 63;
        size_t base = (size_t)n * 2560 + b;
#pragma unroll
        for (int j = 0; j < 10; ++j) {
            T[base + (size_t)(kb + j) * 64] = accA[rr][j];
            T[base + (size_t)(20 + kb + j) * 64] = accB[rr][j];
        }
    }
}

__device__ __forceinline__ void fma4(float4& a, float w, const float4 v) {
    a.x += w * v.x; a.y += w * v.y; a.z += w * v.z; a.w += w * v.w;
}
__device__ __forceinline__ float gelu_elu(float v) {
    float g = 0.5f * v * (1.0f + erff(v * 0.70710678118654752f));   // exact GELU
    return g > 0.0f ? g : expm1f(g);                                 // ELU
}

// ---------------- batched SpMM1 + GELU + ELU, bf16 gather, in-place on Y ----------------
// XCD-pinned slices; scalarized CSR; 8-deep gather of uint2 (4 bf16).
__global__ __launch_bounds__(256) void spmm1_all(
    const uint2* __restrict__ H1u, float4* __restrict__ Y,
    const int* __restrict__ rowptr, const int* __restrict__ csrc, const float* __restrict__ csrw)
{
    int bid = blockIdx.x;
    int w0 = (bid & 7) * 1920 + (bid >> 3);   // 0..15359
    int sl = w0 >> 9;                          // 0..29
    int ng = w0 & 511;
    int br = sl / 5, q = sl - br * 5;

    int gg = br == 1 ? 1 : br == 2 ? 2 : br == 5 ? 3 : 0;
    const int*   rp  = rowptr + gg * (NN + 1);
    const int*   src = csrc + (size_t)gg * EE;
    const float* wts = csrw + (size_t)gg * EE;
    const uint2* h = H1u + (size_t)br * (H1S / 4);   // 320 uint2 per node-row
    float4*      y = Y + (size_t)br * (H1S / 4);     // 320 float4 per node-row

    int wv = __builtin_amdgcn_readfirstlane(threadIdx.x >> 6);
    int lane = threadIdx.x & 63;
    int n = ng * 4 + wv;                       // wave-uniform -> scalar CSR loads
    int off = q * 64 + lane;
    int s0 = rp[n], s1 = rp[n + 1];

    float4 a0 = {0,0,0,0}, a1 = {0,0,0,0}, a2 = {0,0,0,0}, a3 = {0,0,0,0};
    int e = s0;
    for (; e + 8 <= s1; e += 8) {
        int   iA = src[e],   iB = src[e+1], iC = src[e+2], iD = src[e+3];
        int   iE = src[e+4], iF = src[e+5], iG = src[e+6], iH = src[e+7];
        float wA = wts[e],   wB = wts[e+1], wC = wts[e+2], wD = wts[e+3];
        float wE = wts[e+4], wF = wts[e+5], wG = wts[e+6], wH = wts[e+7];
        uint2 u0 = h[iA * 320 + off];
        uint2 u1 = h[iB * 320 + off];
        uint2 u2 = h[iC * 320 + off];
        uint2 u3 = h[iD * 320 + off];
        uint2 u4 = h[iE * 320 + off];
        uint2 u5 = h[iF * 320 + off];
        uint2 u6 = h[iG * 320 + off];
        uint2 u7 = h[iH * 320 + off];
        fma4(a0, wA, ubf4(u0)); fma4(a1, wB, ubf4(u1));
        fma4(a2, wC, ubf4(u2)); fma4(a3, wD, ubf4(u3));
        fma4(a0, wE, ubf4(u4)); fma4(a1, wF, ubf4(u5));
        fma4(a2, wG, ubf4(u6)); fma4(a3, wH, ubf4(u7));
    }
    for (; e + 2 <= s1; e += 2) {
        uint2 u0 = h[src[e] * 320 + off];
        uint2 u1 = h[src[e+1] * 320 + off];
        fma4(a0, wts[e], ubf4(u0)); fma4(a1, wts[e+1], ubf4(u1));
    }
    if (e < s1) fma4(a0, wts[e], ubf4(h[src[e] * 320 + off]));
    a0.x += a1.x + a2.x + a3.x;
    a0.y += a1.y + a2.y + a3.y;
    a0.z += a1.z + a2.z + a3.z;
    a0.w += a1.w + a2.w + a3.w;

    size_t b0 = (size_t)n * 320 + off;
    float4 xv = y[b0];
    float4 r;
    r.x = gelu_elu(a0.x + xv.x);
    r.y = gelu_elu(a0.y + xv.y);
    r.z = gelu_elu(a0.z + xv.z);
    r.w = gelu_elu(a0.w + xv.w);
    y[b0] = r;
}

// ---------------- batched dual GEMM2: [M,20]@[20,7] x2; H2 bf16, padded to 8 ch ----------------
__global__ __launch_bounds__(256) void gemm2_all(
    const float* __restrict__ Y, const float* __restrict__ W2,
    const float* __restrict__ V2, const float* __restrict__ b2,
    unsigned short* __restrict__ H2u, float* __restrict__ YV)
{
    int br = blockIdx.y;
    const float* y  = Y + (size_t)br * H1S;
    unsigned short* h2 = H2u + (size_t)br * H2S;
    float* yv = YV + (size_t)br * YVS;
    __shared__ float w2s[140], v2s[140], b2s[7];
    int t = threadIdx.x;
    if (t < 140) { w2s[t] = W2[br * 140 + t]; v2s[t] = V2[br * 140 + t]; }
    if (t < 7) b2s[t] = b2[br * 7 + t];
    __syncthreads();
    int wv = __builtin_amdgcn_readfirstlane(t >> 6), b = t & 63;
    int n = blockIdx.x * 4 + wv;
    size_t yb = (size_t)n * 1280 + b;
    float yr[20];
#pragma unroll
    for (int k = 0; k < 20; ++k) yr[k] = y[yb + (size_t)k * 64];
    float a[7] = {}, v[7] = {};
#pragma unroll
    for (int k = 0; k < 20; ++k) {
        float yk = yr[k];
#pragma unroll
        for (int c = 0; c < 7; ++c) {
            a[c] += yk * w2s[k * 7 + c];
            v[c] += yk * v2s[k * 7 + c];
        }
    }
    size_t hb = (size_t)n * 512 + b;
#pragma unroll
    for (int c = 0; c < 7; ++c) h2[hb + (size_t)c * 64] = bf16_rne(a[c]);
    h2[hb + 7 * 64] = 0;                          // padding channel
    size_t vb = (size_t)n * 448 + b;
#pragma unroll
    for (int c = 0; c < 7; ++c) yv[vb + (size_t)c * 64] = v[c] + b2s[c];
}

// ---------------- batched SpMM2 + ReLU + softmax(B) -> per-branch P ----------------
// XCD-pinned; scalarized CSR; 8-deep bf16 gather. Row = [8 ch][64 b] u16 = 128 uint2.
__global__ __launch_bounds__(256) void spmm2_all(
    const uint2* __restrict__ H2u, const float* __restrict__ YV,
    const int* __restrict__ rowptr, const int* __restrict__ csrc, const float* __restrict__ csrw,
    float* __restrict__ P)
{
    int bid = blockIdx.x;
    int w0 = (bid & 7) * 768 + (bid >> 3);    // 0..6143
    int sl = w0 >> 9;                          // 0..11
    int ng = w0 & 511;
    int br = sl >> 1, hh = sl & 1;

    int gg = br == 1 ? 1 : br == 2 ? 2 : br == 5 ? 3 : 0;
    const int*   rp  = rowptr + gg * (NN + 1);
    const int*   src = csrc + (size_t)gg * EE;
    const float* wts = csrw + (size_t)gg * EE;
    const uint2* h2 = H2u + (size_t)br * (H2S / 4);   // 128 uint2 per node-row
    const float* yv = YV + (size_t)br * YVS;
    float* p = P + (size_t)br * YVS;

    int wv = __builtin_amdgcn_readfirstlane(threadIdx.x >> 6);
    int lane = threadIdx.x & 63;
    int n = ng * 4 + wv;
    int s = hh * 64 + lane;          // uint2 slot in the 128-slot row
    int c = s >> 4;                  // 0..7 (7 = padding)
    int bq = lane & 15;              // b quad
    int s0 = rp[n], s1 = rp[n + 1];

    float4 a0 = {0,0,0,0}, a1 = {0,0,0,0}, a2 = {0,0,0,0}, a3 = {0,0,0,0};
    int e = s0;
    for (; e + 8 <= s1; e += 8) {
        int   iA = src[e],   iB = src[e+1], iC = src[e+2], iD = src[e+3];
        int   iE = src[e+4], iF = src[e+5], iG = src[e+6], iH = src[e+7];
        float wA = wts[e],   wB = wts[e+1], wC = wts[e+2], wD = wts[e+3];
        float wE = wts[e+4], wF = wts[e+5], wG = wts[e+6], wH = wts[e+7];
        uint2 u0 = h2[iA * 128 + s];
        uint2 u1 = h2[iB * 128 + s];
        uint2 u2 = h2[iC * 128 + s];
        uint2 u3 = h2[iD * 128 + s];
        uint2 u4 = h2[iE * 128 + s];
        uint2 u5 = h2[iF * 128 + s];
        uint2 u6 = h2[iG * 128 + s];
        uint2 u7 = h2[iH * 128 + s];
        fma4(a0, wA, ubf4(u0)); fma4(a1, wB, ubf4(u1));
        fma4(a2, wC, ubf4(u2)); fma4(a3, wD, ubf4(u3));
        fma4(a0, wE, ubf4(u4)); fma4(a1, wF, ubf4(u5));
        fma4(a2, wG, ubf4(u6)); fma4(a3, wH, ubf4(u7));
    }
    for (; e < s1; ++e) fma4(a0, wts[e], ubf4(h2[src[e] * 128 + s]));
    a0.x += a1.x + a2.x + a3.x;
    a0.y += a1.y + a2.y + a3.y;
    a0.z += a1.z + a2.z + a3.z;
    a0.w += a1.w + a2.w + a3.w;

    float4 z = {0,0,0,0};
    if (c < 7) {
        float4 yvv = *reinterpret_cast<const float4*>(&yv[(size_t)n * 448 + c * 64 + bq * 4]);
        z.x = fmaxf(a0.x + yvv.x, 0.0f);
        z.y = fmaxf(a0.y + yvv.y, 0.0f);
        z.z = fmaxf(a0.z + yvv.z, 0.0f);
        z.w = fmaxf(a0.w + yvv.w, 0.0f);
    }
    float m = fmaxf(fmaxf(z.x, z.y), fmaxf(z.z, z.w));
#pragma unroll
    for (int o = 8; o > 0; o >>= 1) m = fmaxf(m, __shfl_xor(m, o, 64));
    float4 pz;
    pz.x = expf(z.x - m); pz.y = expf(z.y - m);
    pz.z = expf(z.z - m); pz.w = expf(z.w - m);
    float sm = pz.x + pz.y + pz.z + pz.w;
#pragma unroll
    for (int o = 8; o > 0; o >>= 1) sm += __shfl_xor(sm, o, 64);
    float inv = 1.0f / sm;
    if (c < 7) {
        float4 r = { pz.x * inv, pz.y * inv, pz.z * inv, pz.w * inv };
        *reinterpret_cast<float4*>(&p[(size_t)n * 448 + c * 64 + bq * 4]) = r;
    }
}

// ---------------- wave softmax over 64 lanes (batch axis) ----------------
__device__ __forceinline__ void wave_softmax7(float* z)
{
#pragma unroll
    for (int c = 0; c < 7; ++c) {
        float m = z[c];
#pragma unroll
        for (int o = 32; o > 0; o >>= 1) m = fmaxf(m, __shfl_xor(m, o, 64));
        float p = expf(z[c] - m);
        float s = p;
#pragma unroll
        for (int o = 32; o > 0; o >>= 1) s += __shfl_xor(s, o, 64);
        z[c] = p / s;
    }
}

// ---------------- final: o_lt tail, dense+gnn heads, output [N][C][B] ----------------
__global__ __launch_bounds__(256) void combine_kernel(
    const float* __restrict__ T, const float* __restrict__ P,
    const float* __restrict__ Wl2, const float* __restrict__ bl2,
    const float* __restrict__ Wd, const float* __restrict__ bd,
    const float* __restrict__ Wg, const float* __restrict__ bg,
    float* __restrict__ out)
{
    __shared__ float wl2s[280], bl2s[7], wds[49], bds[7], wgs[49], bgs[7];
    int t = threadIdx.x;
    for (int i = t; i < 280; i += 256) wl2s[i] = Wl2[i];
    if (t < 49) { wds[t] = Wd[t]; wgs[t] = Wg[t]; }
    if (t < 7) { bl2s[t] = bl2[t]; bds[t] = bd[t]; bgs[t] = bg[t]; }
    __syncthreads();

    int wv = t >> 6, b = t & 63;
    int n = blockIdx.x * 4 + wv;
    size_t rbase = (size_t)n * 2560 + b;   // T is [n][40][b]
    float tr[40];
#pragma unroll
    for (int j = 0; j < 40; ++j) tr[j] = T[rbase + (size_t)j * 64];

    float u[7];
#pragma unroll
    for (int c = 0; c < 7; ++c) u[c] = bl2s[c];
    for (int j = 0; j < 40; ++j) {
        float tv = tr[j];
#pragma unroll
        for (int c = 0; c < 7; ++c) u[c] += tv * wl2s[j * 7 + c];
    }
    wave_softmax7(u);   // o_lt

    size_t sbase = (size_t)n * 448 + b;
    float sd[7], sg[7];
#pragma unroll
    for (int c = 0; c < 7; ++c) {
        size_t o = sbase + (size_t)c * 64;
        sg[c] = P[o] + P[YVS + o] + P[2 * YVS + o] + P[3 * YVS + o] + P[4 * YVS + o];
        sd[c] = 2.0f * P[5 * YVS + o] + 2.0f * u[c];
    }
    float dv[7];
#pragma unroll
    for (int c = 0; c < 7; ++c) dv[c] = bds[c];
#pragma unroll
    for (int c2 = 0; c2 < 7; ++c2) {
        float s = sd[c2];
#pragma unroll
        for (int c = 0; c < 7; ++c) dv[c] += s * wds[c2 * 7 + c];
    }
    wave_softmax7(dv);  // out_dense

    float gv[7];
#pragma unroll
    for (int c = 0; c < 7; ++c) gv[c] = bgs[c];
#pragma unroll
    for (int c2 = 0; c2 < 7; ++c2) {
        float s = sg[c2];
#pragma unroll
        for (int c = 0; c < 7; ++c) gv[c] += s * wgs[c2 * 7 + c];
    }
    wave_softmax7(gv);  // out_gnn

    size_t ob = (size_t)n * 448 + b;
#pragma unroll
    for (int c = 0; c < 7; ++c) out[ob + (size_t)c * 64] = dv[c] + gv[c];
}

// ---------------- host ----------------
extern "C" void kernel_launch(void* const* d_in, const int* in_sizes, int n_in,
                              void* d_out, int out_size, void* d_ws, size_t ws_size,
                              hipStream_t stream)
{
    (void)in_sizes; (void)n_in; (void)out_size; (void)ws_size;
    const int* e0 = (const int*)d_in[0];
    const int* e1 = (const int*)d_in[1];
    const int* e2 = (const int*)d_in[2];
    const int* e3 = (const int*)d_in[3];
    const float* X0 = (const float*)d_in[4];
    const float* X1 = (const float*)d_in[5];
    const float* X2 = (const float*)d_in[6];
    const float* X3 = (const float*)d_in[7];
    const float* X4 = (const float*)d_in[8];
    const float* X5 = (const float*)d_in[9];
    const float* W1  = (const float*)d_in[10];
    const float* V1  = (const float*)d_in[11];
    const float* b1  = (const float*)d_in[12];
    const float* W2  = (const float*)d_in[13];
    const float* V2  = (const float*)d_in[14];
    const float* b2  = (const float*)d_in[15];
    const float* Wlt = (const float*)d_in[16];
    const float* blt = (const float*)d_in[17];
    const float* Wl2 = (const float*)d_in[18];
    const float* bl2 = (const float*)d_in[19];
    const float* Wd  = (const float*)d_in[20];
    const float* bd  = (const float*)d_in[21];
    const float* Wg  = (const float*)d_in[22];
    const float* bg  = (const float*)d_in[23];

    char* ws = (char*)d_ws;
    int*   deg    = (int*)(ws + OFF_DEG);
    int*   cursor = (int*)(ws + OFF_CURSOR);
    float* dinv   = (float*)(ws + OFF_DINV);
    int*   rowptr = (int*)(ws + OFF_ROWPTR);
    int*   csrc   = (int*)(ws + OFF_CSRC);
    float* csrw   = (float*)(ws + OFF_CSRW);
    unsigned short* H1u = (unsigned short*)(ws + OFF_H1);
    float* Pbuf   = (float*)(ws + OFF_P);
    float* Y      = (float*)(ws + OFF_Y);
    unsigned short* H2u = (unsigned short*)(ws + OFF_H2);
    float* YV     = (float*)(ws + OFF_YV);
    float* Tbuf   = (float*)(ws + OFF_T);

    hipMemsetAsync(d_ws, 0, ZBYTES, stream);

    count_deg_kernel<<<1024, 256, 0, stream>>>(e0 + EE, e1 + EE, e2 + EE, e3 + EE, deg);
    scan_dinv_kernel<<<4, 256, 0, stream>>>(deg, rowptr, dinv);
    fill_csr_kernel<<<1024, 256, 0, stream>>>(e0, e0 + EE, e1, e1 + EE, e2, e2 + EE,
                                              e3, e3 + EE, rowptr, cursor, dinv, csrc, csrw);

    gemm48_main<<<dim3(256, 6), 512, 0, stream>>>(X0, X1, X2, X3, X4, X5,
                                                  W1, V1, b1, H1u, Y);
    gemm48_lt<<<256, 512, 0, stream>>>(X5, Wlt, blt, Tbuf);
    spmm1_all<<<15360, 256, 0, stream>>>((const uint2*)H1u, (float4*)Y,
                                         rowptr, csrc, csrw);
    gemm2_all<<<dim3(512, 6), 256, 0, stream>>>(Y, W2, V2, b2, H2u, YV);
    spmm2_all<<<6144, 256, 0, stream>>>((const uint2*)H2u, YV,
                                        rowptr, csrc, csrw, Pbuf);
    combine_kernel<<<512, 256, 0, stream>>>(Tbuf, Pbuf, Wl2, bl2, Wd, bd, Wg, bg,
                                            (float*)d_out);
}

// Round 12
// 254.609 us; speedup vs baseline: 7.9534x; 1.1379x over previous
//
#include <hip/hip_runtime.h>
#include <math.h>

// Problem dims
#define NN   2048      // nodes
#define BB   64        // batch
#define FF   48        // in features
#define EE   65536     // edges per graph
#define CC   7         // out channels
#define HH   20        // hidden

// ---- ws layout (bytes), ws_size = 256 MiB ----
#define OFF_DEG      0u
#define OFF_CURSOR   32768u
#define ZBYTES       65536u
#define OFF_DINV     65536u            // float[4][N]
#define OFF_ROWPTR   98304u            // int[4][N+1]
#define OFF_CSRC     131584u           // int[4][E]
#define OFF_CSRW     1180160u          // float[4][E]
#define OFF_H1       2228736u          // 6 x bf16[N][20][B] (u16) = 6 x 5.24MB
#define OFF_P        OFF_H1            // 6 x float[N][7][B], overlays H1 (dead at spmm2)
#define OFF_Y        65143296u         // 6 x bf16[N][20][B] (u16); init = xV+b, act in place
#define OFF_H2       128057856u        // 6 x bf16[N][8][B] (u16, padded to 8 ch) = 6 x 2MB
#define OFF_YV       153223680u        // 6 x float[N][7][B]
#define OFF_T        175243776u        // float[N][40][B] 21MB
// end = 196,215,296 B < 256 MiB

#define H1S  2621440u   // elements per branch in H1(u16) / Y(u16)
#define H2S  1048576u   // u16 elements per branch in H2 (padded)
#define YVS  917504u    // floats per branch in YV / P

typedef __attribute__((ext_vector_type(8))) short bf16x8;
typedef __attribute__((ext_vector_type(4))) float f32x4;
#define MFMA32 __builtin_amdgcn_mfma_f32_16x16x32_bf16

__device__ __forceinline__ unsigned short bf16_rne(float x) {
    unsigned u = __float_as_uint(x);
    u += 0x7fffu + ((u >> 16) & 1u);
    return (unsigned short)(u >> 16);
}
__device__ __forceinline__ float4 ubf4(uint2 u) {
    float4 r;
    r.x = __uint_as_float(u.x << 16);
    r.y = __uint_as_float(u.x & 0xffff0000u);
    r.z = __uint_as_float(u.y << 16);
    r.w = __uint_as_float(u.y & 0xffff0000u);
    return r;
}

// ---------------- CSR build ----------------
__global__ __launch_bounds__(256) void count_deg_kernel(
    const int* __restrict__ c0, const int* __restrict__ c1,
    const int* __restrict__ c2, const int* __restrict__ c3, int* __restrict__ deg)
{
    int idx = blockIdx.x * 256 + threadIdx.x;          // 4*E threads
    int g = idx >> 16, e = idx & 0xFFFF;
    const int* cp = g == 0 ? c0 : g == 1 ? c1 : g == 2 ? c2 : c3;
    atomicAdd(&deg[(g << 11) + cp[e]], 1);
}

__global__ __launch_bounds__(256) void scan_dinv_kernel(
    const int* __restrict__ deg, int* __restrict__ rowptr, float* __restrict__ dinv)
{
    int g = blockIdx.x, t = threadIdx.x;
    __shared__ int part[256];
    const int* d = deg + g * NN;
    int loc[8]; int s = 0;
#pragma unroll
    for (int j = 0; j < 8; ++j) { loc[j] = d[t * 8 + j]; s += loc[j]; }
    part[t] = s; __syncthreads();
    for (int off = 1; off < 256; off <<= 1) {
        int v = (t >= off) ? part[t - off] : 0;
        __syncthreads();
        part[t] += v;
        __syncthreads();
    }
    int run = (t > 0) ? part[t - 1] : 0;
    int* rp = rowptr + g * (NN + 1);
#pragma unroll
    for (int j = 0; j < 8; ++j) {
        int n = t * 8 + j;
        rp[n] = run; run += loc[j];
        dinv[g * NN + n] = loc[j] > 0 ? 1.0f / sqrtf((float)loc[j]) : 0.0f;
    }
    if (t == 255) rp[NN] = run;
}

__global__ __launch_bounds__(256) void fill_csr_kernel(
    const int* __restrict__ r0, const int* __restrict__ c0,
    const int* __restrict__ r1, const int* __restrict__ c1,
    const int* __restrict__ r2, const int* __restrict__ c2,
    const int* __restrict__ r3, const int* __restrict__ c3,
    const int* __restrict__ rowptr, int* __restrict__ cursor,
    const float* __restrict__ dinv, int* __restrict__ csrc, float* __restrict__ cw)
{
    int idx = blockIdx.x * 256 + threadIdx.x;
    int g = idx >> 16, e = idx & 0xFFFF;
    const int* rp = g == 0 ? r0 : g == 1 ? r1 : g == 2 ? r2 : r3;
    const int* cp = g == 0 ? c0 : g == 1 ? c1 : g == 2 ? c2 : c3;
    int r = rp[e], c = cp[e];
    int pos = atomicAdd(&cursor[(g << 11) + c], 1);
    int o = rowptr[g * (NN + 1) + c] + pos;
    csrc[(g << 16) + o] = r;
    cw[(g << 16) + o] = dinv[(g << 11) + r] * dinv[(g << 11) + c];
}

// ---------------- MFMA dual GEMM (6 branches): [M,48]@[48,20] x2 ----------------
// Per 16-row tile: K=48 padded to 2x32, N=20 padded to 2x16 -> 8 MFMAs {W,V}.
// A: lane row = l&15, k = 32c + (l>>4)*8 + j. B: lane col = l&15, same k map
// (identical k-map for A and B => any intra-lane k-order assumption cancels).
// C/D: col = lane&15, row = (lane>>4)*4 + reg  [m89-verified].
// Block = 4 waves = 4 nodes; wave does its node's 4 batch-16 tiles. No LDS.
__global__ __launch_bounds__(256) void gemm48_mfma(
    const float* __restrict__ X0, const float* __restrict__ X1,
    const float* __restrict__ X2, const float* __restrict__ X3,
    const float* __restrict__ X4, const float* __restrict__ X5,
    const float* __restrict__ W1, const float* __restrict__ V1,
    const float* __restrict__ b1,
    unsigned short* __restrict__ H1u, unsigned short* __restrict__ Yu)
{
    int br = blockIdx.y;
    const float* X = br == 0 ? X0 : br == 1 ? X1 : br == 2 ? X2 :
                     br == 3 ? X3 : br == 4 ? X4 : X5;
    const float* Wa = W1 + br * 960;
    const float* Wb = V1 + br * 960;

    int t = threadIdx.x;
    int w = t >> 6, lane = t & 63;
    int node = blockIdx.x * 4 + w;
    int col = lane & 15;
    int grp = lane >> 4;

    // B-frags (built once): [chunk][ntile] for W and V
    bf16x8 bw[2][2], bv[2][2];
#pragma unroll
    for (int c = 0; c < 2; ++c)
#pragma unroll
        for (int nt = 0; nt < 2; ++nt) {
            int n = nt * 16 + col;
#pragma unroll
            for (int j = 0; j < 8; ++j) {
                int k = c * 32 + grp * 8 + j;
                float vw = 0.0f, vv = 0.0f;
                if (n < 20 && k < 48) { vw = Wa[k * 20 + n]; vv = Wb[k * 20 + n]; }
                bw[c][nt][j] = (short)bf16_rne(vw);
                bv[c][nt][j] = (short)bf16_rne(vv);
            }
        }
    float bias0 = b1[br * 20 + col];                       // kout = col (<16)
    float bias1 = col < 4 ? b1[br * 20 + 16 + col] : 0.0f; // kout = 16+col

#pragma unroll
    for (int tb = 0; tb < 4; ++tb) {
        int b0 = tb * 16;
        const float* xr = X + ((size_t)node * 64 + b0 + col) * 48;

        // A-frag chunk0 (k 0..31)
        bf16x8 a0;
        {
            float4 xa = *reinterpret_cast<const float4*>(xr + grp * 8);
            float4 xb = *reinterpret_cast<const float4*>(xr + grp * 8 + 4);
            a0[0] = (short)bf16_rne(xa.x); a0[1] = (short)bf16_rne(xa.y);
            a0[2] = (short)bf16_rne(xa.z); a0[3] = (short)bf16_rne(xa.w);
            a0[4] = (short)bf16_rne(xb.x); a0[5] = (short)bf16_rne(xb.y);
            a0[6] = (short)bf16_rne(xb.z); a0[7] = (short)bf16_rne(xb.w);
        }
        // A-frag chunk1 (k 32..63, valid 32..47 -> grp<2)
        bf16x8 a1 = {0, 0, 0, 0, 0, 0, 0, 0};
        if (grp < 2) {
            float4 xc = *reinterpret_cast<const float4*>(xr + 32 + grp * 8);
            float4 xd = *reinterpret_cast<const float4*>(xr + 32 + grp * 8 + 4);
            a1[0] = (short)bf16_rne(xc.x); a1[1] = (short)bf16_rne(xc.y);
            a1[2] = (short)bf16_rne(xc.z); a1[3] = (short)bf16_rne(xc.w);
            a1[4] = (short)bf16_rne(xd.x); a1[5] = (short)bf16_rne(xd.y);
            a1[6] = (short)bf16_rne(xd.z); a1[7] = (short)bf16_rne(xd.w);
        }

        f32x4 aw0 = {0,0,0,0}, aw1 = {0,0,0,0}, av0 = {0,0,0,0}, av1 = {0,0,0,0};
        aw0 = MFMA32(a0, bw[0][0], aw0, 0, 0, 0);
        aw1 = MFMA32(a0, bw[0][1], aw1, 0, 0, 0);
        av0 = MFMA32(a0, bv[0][0], av0, 0, 0, 0);
        av1 = MFMA32(a0, bv[0][1], av1, 0, 0, 0);
        aw0 = MFMA32(a1, bw[1][0], aw0, 0, 0, 0);
        aw1 = MFMA32(a1, bw[1][1], aw1, 0, 0, 0);
        av0 = MFMA32(a1, bv[1][0], av0, 0, 0, 0);
        av1 = MFMA32(a1, bv[1][1], av1, 0, 0, 0);

        // store: lane holds kout=col (+16), b = b0 + grp*4 + reg (4 consecutive)
        size_t base = (size_t)br * H1S + (size_t)node * 1280 + b0 + grp * 4;
        uint2 pk;
        pk.x = (unsigned)bf16_rne(aw0[0]) | ((unsigned)bf16_rne(aw0[1]) << 16);
        pk.y = (unsigned)bf16_rne(aw0[2]) | ((unsigned)bf16_rne(aw0[3]) << 16);
        *reinterpret_cast<uint2*>(H1u + base + (size_t)col * 64) = pk;
        pk.x = (unsigned)bf16_rne(av0[0] + bias0) | ((unsigned)bf16_rne(av0[1] + bias0) << 16);
        pk.y = (unsigned)bf16_rne(av0[2] + bias0) | ((unsigned)bf16_rne(av0[3] + bias0) << 16);
        *reinterpret_cast<uint2*>(Yu + base + (size_t)col * 64) = pk;
        if (col < 4) {
            int k2 = 16 + col;
            pk.x = (unsigned)bf16_rne(aw1[0]) | ((unsigned)bf16_rne(aw1[1]) << 16);
            pk.y = (unsigned)bf16_rne(aw1[2]) | ((unsigned)bf16_rne(aw1[3]) << 16);
            *reinterpret_cast<uint2*>(H1u + base + (size_t)k2 * 64) = pk;
            pk.x = (unsigned)bf16_rne(av1[0] + bias1) | ((unsigned)bf16_rne(av1[1] + bias1) << 16);
            pk.y = (unsigned)bf16_rne(av1[2] + bias1) | ((unsigned)bf16_rne(av1[3] + bias1) << 16);
            *reinterpret_cast<uint2*>(Yu + base + (size_t)k2 * 64) = pk;
        }
    }
}

// ---------------- o_lt GEMM: T = Xlt@Wlt + blt, literal stride 40 (r9-proven) ----------------
__global__ __launch_bounds__(512, 4) void gemm48_lt(
    const float* __restrict__ X, const float* __restrict__ Wlt,
    const float* __restrict__ blt, float* __restrict__ T)
{
    __shared__ float xs[512 * 24];
    int t = threadIdx.x;
    const float4* Xv = reinterpret_cast<const float4*>(X) + (size_t)blockIdx.x * 6144;

    int r = t & 255;
    int kb = __builtin_amdgcn_readfirstlane((t >> 8) * 10);
    const float* wap = Wlt + kb;          // cols kb..kb+9
    const float* wbp = Wlt + 20 + kb;     // cols 20+kb..20+kb+9

    float accA[2][10], accB[2][10];
#pragma unroll
    for (int j = 0; j < 10; ++j) {
        accA[0][j] = blt[kb + j];      accA[1][j] = accA[0][j];
        accB[0][j] = blt[20 + kb + j]; accB[1][j] = accB[0][j];
    }

#pragma unroll
    for (int ph = 0; ph < 2; ++ph) {
        if (ph) __syncthreads();
#pragma unroll
        for (int i = 0; i < 6; ++i) {
            int fl4 = i * 512 + t;
            int rr = fl4 / 6, fq = fl4 - rr * 6;
            float4 v = Xv[rr * 12 + ph * 6 + fq];
            *reinterpret_cast<float4*>(&xs[fl4 * 4]) = v;
        }
        __syncthreads();
#pragma unroll
        for (int fq = 0; fq < 6; ++fq) {
            float4 xA = *reinterpret_cast<const float4*>(&xs[r * 24 + fq * 4]);
            float4 xB = *reinterpret_cast<const float4*>(&xs[(r + 256) * 24 + fq * 4]);
#pragma unroll
            for (int ff = 0; ff < 4; ++ff) {
                int f = ph * 24 + fq * 4 + ff;
                float a0 = ff == 0 ? xA.x : ff == 1 ? xA.y : ff == 2 ? xA.z : xA.w;
                float a1 = ff == 0 ? xB.x : ff == 1 ? xB.y : ff == 2 ? xB.z : xB.w;
                const float* wr = wap + f * 40;
                const float* vr = wbp + f * 40;
#pragma unroll
                for (int j = 0; j < 10; ++j) {
                    float w = wr[j], v2 = vr[j];
                    accA[0][j] += w * a0;  accA[1][j] += w * a1;
                    accB[0][j] += v2 * a0; accB[1][j] += v2 * a1;
                }
            }
        }
    }

    int n0 = blockIdx.x * 8;
#pragma unroll
    for (int rr = 0; rr < 2; ++rr) {
        int row = r + rr * 256;
        int n = n0 + (row >> 6), b = row & 63;
        size_t base = (size_t)n * 2560 + b;
#pragma unroll
        for (int j = 0; j < 10; ++j) {
            T[base + (size_t)(kb + j) * 64] = accA[rr][j];
            T[base + (size_t)(20 + kb + j) * 64] = accB[rr][j];
        }
    }
}

__device__ __forceinline__ void fma4(float4& a, float w, const float4 v) {
    a.x += w * v.x; a.y += w * v.y; a.z += w * v.z; a.w += w * v.w;
}
__device__ __forceinline__ float gelu_elu(float v) {
    float g = 0.5f * v * (1.0f + erff(v * 0.70710678118654752f));   // exact GELU
    return g > 0.0f ? g : expm1f(g);                                 // ELU
}

// ---------------- batched SpMM1 + GELU + ELU, bf16 gather, in-place on bf16 Y ----------------
// XCD-pinned slices; scalarized CSR; 8-deep gather of uint2 (4 bf16).
__global__ __launch_bounds__(256) void spmm1_all(
    const uint2* __restrict__ H1u, uint2* __restrict__ Y,
    const int* __restrict__ rowptr, const int* __restrict__ csrc, const float* __restrict__ csrw)
{
    int bid = blockIdx.x;
    int w0 = (bid & 7) * 1920 + (bid >> 3);   // 0..15359
    int sl = w0 >> 9;                          // 0..29
    int ng = w0 & 511;
    int br = sl / 5, q = sl - br * 5;

    int gg = br == 1 ? 1 : br == 2 ? 2 : br == 5 ? 3 : 0;
    const int*   rp  = rowptr + gg * (NN + 1);
    const int*   src = csrc + (size_t)gg * EE;
    const float* wts = csrw + (size_t)gg * EE;
    const uint2* h = H1u + (size_t)br * (H1S / 4);   // 320 uint2 per node-row
    uint2*       y = Y + (size_t)br * (H1S / 4);     // 320 uint2 per node-row

    int wv = __builtin_amdgcn_readfirstlane(threadIdx.x >> 6);
    int lane = threadIdx.x & 63;
    int n = ng * 4 + wv;                       // wave-uniform -> scalar CSR loads
    int off = q * 64 + lane;
    int s0 = rp[n], s1 = rp[n + 1];

    float4 a0 = {0,0,0,0}, a1 = {0,0,0,0}, a2 = {0,0,0,0}, a3 = {0,0,0,0};
    int e = s0;
    for (; e + 8 <= s1; e += 8) {
        int   iA = src[e],   iB = src[e+1], iC = src[e+2], iD = src[e+3];
        int   iE = src[e+4], iF = src[e+5], iG = src[e+6], iH = src[e+7];
        float wA = wts[e],   wB = wts[e+1], wC = wts[e+2], wD = wts[e+3];
        float wE = wts[e+4], wF = wts[e+5], wG = wts[e+6], wH = wts[e+7];
        uint2 u0 = h[iA * 320 + off];
        uint2 u1 = h[iB * 320 + off];
        uint2 u2 = h[iC * 320 + off];
        uint2 u3 = h[iD * 320 + off];
        uint2 u4 = h[iE * 320 + off];
        uint2 u5 = h[iF * 320 + off];
        uint2 u6 = h[iG * 320 + off];
        uint2 u7 = h[iH * 320 + off];
        fma4(a0, wA, ubf4(u0)); fma4(a1, wB, ubf4(u1));
        fma4(a2, wC, ubf4(u2)); fma4(a3, wD, ubf4(u3));
        fma4(a0, wE, ubf4(u4)); fma4(a1, wF, ubf4(u5));
        fma4(a2, wG, ubf4(u6)); fma4(a3, wH, ubf4(u7));
    }
    for (; e + 2 <= s1; e += 2) {
        uint2 u0 = h[src[e] * 320 + off];
        uint2 u1 = h[src[e+1] * 320 + off];
        fma4(a0, wts[e], ubf4(u0)); fma4(a1, wts[e+1], ubf4(u1));
    }
    if (e < s1) fma4(a0, wts[e], ubf4(h[src[e] * 320 + off]));
    a0.x += a1.x + a2.x + a3.x;
    a0.y += a1.y + a2.y + a3.y;
    a0.z += a1.z + a2.z + a3.z;
    a0.w += a1.w + a2.w + a3.w;

    size_t b0 = (size_t)n * 320 + off;
    float4 xv = ubf4(y[b0]);
    float4 r;
    r.x = gelu_elu(a0.x + xv.x);
    r.y = gelu_elu(a0.y + xv.y);
    r.z = gelu_elu(a0.z + xv.z);
    r.w = gelu_elu(a0.w + xv.w);
    uint2 pk;
    pk.x = (unsigned)bf16_rne(r.x) | ((unsigned)bf16_rne(r.y) << 16);
    pk.y = (unsigned)bf16_rne(r.z) | ((unsigned)bf16_rne(r.w) << 16);
    y[b0] = pk;
}

// ---------------- batched dual GEMM2: [M,20]@[20,7] x2; Y bf16 in, H2 bf16 out ----------------
__global__ __launch_bounds__(256) void gemm2_all(
    const unsigned short* __restrict__ Yu, const float* __restrict__ W2,
    const float* __restrict__ V2, const float* __restrict__ b2,
    unsigned short* __restrict__ H2u, float* __restrict__ YV)
{
    int br = blockIdx.y;
    const unsigned short* y = Yu + (size_t)br * H1S;
    unsigned short* h2 = H2u + (size_t)br * H2S;
    float* yv = YV + (size_t)br * YVS;
    __shared__ float w2s[140], v2s[140], b2s[7];
    int t = threadIdx.x;
    if (t < 140) { w2s[t] = W2[br * 140 + t]; v2s[t] = V2[br * 140 + t]; }
    if (t < 7) b2s[t] = b2[br * 7 + t];
    __syncthreads();
    int wv = __builtin_amdgcn_readfirstlane(t >> 6), b = t & 63;
    int n = blockIdx.x * 4 + wv;
    size_t yb = (size_t)n * 1280 + b;
    float yr[20];
#pragma unroll
    for (int k = 0; k < 20; ++k)
        yr[k] = __uint_as_float((unsigned)y[yb + (size_t)k * 64] << 16);
    float a[7] = {}, v[7] = {};
#pragma unroll
    for (int k = 0; k < 20; ++k) {
        float yk = yr[k];
#pragma unroll
        for (int c = 0; c < 7; ++c) {
            a[c] += yk * w2s[k * 7 + c];
            v[c] += yk * v2s[k * 7 + c];
        }
    }
    size_t hb = (size_t)n * 512 + b;
#pragma unroll
    for (int c = 0; c < 7; ++c) h2[hb + (size_t)c * 64] = bf16_rne(a[c]);
    h2[hb + 7 * 64] = 0;                          // padding channel
    size_t vb = (size_t)n * 448 + b;
#pragma unroll
    for (int c = 0; c < 7; ++c) yv[vb + (size_t)c * 64] = v[c] + b2s[c];
}

// ---------------- batched SpMM2 + ReLU + softmax(B) -> per-branch P ----------------
// XCD-pinned; scalarized CSR; 8-deep bf16 gather. Row = [8 ch][64 b] u16 = 128 uint2.
__global__ __launch_bounds__(256) void spmm2_all(
    const uint2* __restrict__ H2u, const float* __restrict__ YV,
    const int* __restrict__ rowptr, const int* __restrict__ csrc, const float* __restrict__ csrw,
    float* __restrict__ P)
{
    int bid = blockIdx.x;
    int w0 = (bid & 7) * 768 + (bid >> 3);    // 0..6143
    int sl = w0 >> 9;                          // 0..11
    int ng = w0 & 511;
    int br = sl >> 1, hh = sl & 1;

    int gg = br == 1 ? 1 : br == 2 ? 2 : br == 5 ? 3 : 0;
    const int*   rp  = rowptr + gg * (NN + 1);
    const int*   src = csrc + (size_t)gg * EE;
    const float* wts = csrw + (size_t)gg * EE;
    const uint2* h2 = H2u + (size_t)br * (H2S / 4);   // 128 uint2 per node-row
    const float* yv = YV + (size_t)br * YVS;
    float* p = P + (size_t)br * YVS;

    int wv = __builtin_amdgcn_readfirstlane(threadIdx.x >> 6);
    int lane = threadIdx.x & 63;
    int n = ng * 4 + wv;
    int s = hh * 64 + lane;          // uint2 slot in the 128-slot row
    int c = s >> 4;                  // 0..7 (7 = padding)
    int bq = lane & 15;              // b quad
    int s0 = rp[n], s1 = rp[n + 1];

    float4 a0 = {0,0,0,0}, a1 = {0,0,0,0}, a2 = {0,0,0,0}, a3 = {0,0,0,0};
    int e = s0;
    for (; e + 8 <= s1; e += 8) {
        int   iA = src[e],   iB = src[e+1], iC = src[e+2], iD = src[e+3];
        int   iE = src[e+4], iF = src[e+5], iG = src[e+6], iH = src[e+7];
        float wA = wts[e],   wB = wts[e+1], wC = wts[e+2], wD = wts[e+3];
        float wE = wts[e+4], wF = wts[e+5], wG = wts[e+6], wH = wts[e+7];
        uint2 u0 = h2[iA * 128 + s];
        uint2 u1 = h2[iB * 128 + s];
        uint2 u2 = h2[iC * 128 + s];
        uint2 u3 = h2[iD * 128 + s];
        uint2 u4 = h2[iE * 128 + s];
        uint2 u5 = h2[iF * 128 + s];
        uint2 u6 = h2[iG * 128 + s];
        uint2 u7 = h2[iH * 128 + s];
        fma4(a0, wA, ubf4(u0)); fma4(a1, wB, ubf4(u1));
        fma4(a2, wC, ubf4(u2)); fma4(a3, wD, ubf4(u3));
        fma4(a0, wE, ubf4(u4)); fma4(a1, wF, ubf4(u5));
        fma4(a2, wG, ubf4(u6)); fma4(a3, wH, ubf4(u7));
    }
    for (; e < s1; ++e) fma4(a0, wts[e], ubf4(h2[src[e] * 128 + s]));
    a0.x += a1.x + a2.x + a3.x;
    a0.y += a1.y + a2.y + a3.y;
    a0.z += a1.z + a2.z + a3.z;
    a0.w += a1.w + a2.w + a3.w;

    float4 z = {0,0,0,0};
    if (c < 7) {
        float4 yvv = *reinterpret_cast<const float4*>(&yv[(size_t)n * 448 + c * 64 + bq * 4]);
        z.x = fmaxf(a0.x + yvv.x, 0.0f);
        z.y = fmaxf(a0.y + yvv.y, 0.0f);
        z.z = fmaxf(a0.z + yvv.z, 0.0f);
        z.w = fmaxf(a0.w + yvv.w, 0.0f);
    }
    float m = fmaxf(fmaxf(z.x, z.y), fmaxf(z.z, z.w));
#pragma unroll
    for (int o = 8; o > 0; o >>= 1) m = fmaxf(m, __shfl_xor(m, o, 64));
    float4 pz;
    pz.x = expf(z.x - m); pz.y = expf(z.y - m);
    pz.z = expf(z.z - m); pz.w = expf(z.w - m);
    float sm = pz.x + pz.y + pz.z + pz.w;
#pragma unroll
    for (int o = 8; o > 0; o >>= 1) sm += __shfl_xor(sm, o, 64);
    float inv = 1.0f / sm;
    if (c < 7) {
        float4 r = { pz.x * inv, pz.y * inv, pz.z * inv, pz.w * inv };
        *reinterpret_cast<float4*>(&p[(size_t)n * 448 + c * 64 + bq * 4]) = r;
    }
}

// ---------------- wave softmax over 64 lanes (batch axis) ----------------
__device__ __forceinline__ void wave_softmax7(float* z)
{
#pragma unroll
    for (int c = 0; c < 7; ++c) {
        float m = z[c];
#pragma unroll
        for (int o = 32; o > 0; o >>= 1) m = fmaxf(m, __shfl_xor(m, o, 64));
        float p = expf(z[c] - m);
        float s = p;
#pragma unroll
        for (int o = 32; o > 0; o >>= 1) s += __shfl_xor(s, o, 64);
        z[c] = p / s;
    }
}

// ---------------- final: o_lt tail, dense+gnn heads, output [N][C][B] ----------------
__global__ __launch_bounds__(256) void combine_kernel(
    const float* __restrict__ T, const float* __restrict__ P,
    const float* __restrict__ Wl2, const float* __restrict__ bl2,
    const float* __restrict__ Wd, const float* __restrict__ bd,
    const float* __restrict__ Wg, const float* __restrict__ bg,
    float* __restrict__ out)
{
    __shared__ float wl2s[280], bl2s[7], wds[49], bds[7], wgs[49], bgs[7];
    int t = threadIdx.x;
    for (int i = t; i < 280; i += 256) wl2s[i] = Wl2[i];
    if (t < 49) { wds[t] = Wd[t]; wgs[t] = Wg[t]; }
    if (t < 7) { bl2s[t] = bl2[t]; bds[t] = bd[t]; bgs[t] = bg[t]; }
    __syncthreads();

    int wv = t >> 6, b = t & 63;
    int n = blockIdx.x * 4 + wv;
    size_t rbase = (size_t)n * 2560 + b;   // T is [n][40][b]
    float tr[40];
#pragma unroll
    for (int j = 0; j < 40; ++j) tr[j] = T[rbase + (size_t)j * 64];

    float u[7];
#pragma unroll
    for (int c = 0; c < 7; ++c) u[c] = bl2s[c];
    for (int j = 0; j < 40; ++j) {
        float tv = tr[j];
#pragma unroll
        for (int c = 0; c < 7; ++c) u[c] += tv * wl2s[j * 7 + c];
    }
    wave_softmax7(u);   // o_lt

    size_t sbase = (size_t)n * 448 + b;
    float sd[7], sg[7];
#pragma unroll
    for (int c = 0; c < 7; ++c) {
        size_t o = sbase + (size_t)c * 64;
        sg[c] = P[o] + P[YVS + o] + P[2 * YVS + o] + P[3 * YVS + o] + P[4 * YVS + o];
        sd[c] = 2.0f * P[5 * YVS + o] + 2.0f * u[c];
    }
    float dv[7];
#pragma unroll
    for (int c = 0; c < 7; ++c) dv[c] = bds[c];
#pragma unroll
    for (int c2 = 0; c2 < 7; ++c2) {
        float s = sd[c2];
#pragma unroll
        for (int c = 0; c < 7; ++c) dv[c] += s * wds[c2 * 7 + c];
    }
    wave_softmax7(dv);  // out_dense

    float gv[7];
#pragma unroll
    for (int c = 0; c < 7; ++c) gv[c] = bgs[c];
#pragma unroll
    for (int c2 = 0; c2 < 7; ++c2) {
        float s = sg[c2];
#pragma unroll
        for (int c = 0; c < 7; ++c) gv[c] += s * wgs[c2 * 7 + c];
    }
    wave_softmax7(gv);  // out_gnn

    size_t ob = (size_t)n * 448 + b;
#pragma unroll
    for (int c = 0; c < 7; ++c) out[ob + (size_t)c * 64] = dv[c] + gv[c];
}

// ---------------- host ----------------
extern "C" void kernel_launch(void* const* d_in, const int* in_sizes, int n_in,
                              void* d_out, int out_size, void* d_ws, size_t ws_size,
                              hipStream_t stream)
{
    (void)in_sizes; (void)n_in; (void)out_size; (void)ws_size;
    const int* e0 = (const int*)d_in[0];
    const int* e1 = (const int*)d_in[1];
    const int* e2 = (const int*)d_in[2];
    const int* e3 = (const int*)d_in[3];
    const float* X0 = (const float*)d_in[4];
    const float* X1 = (const float*)d_in[5];
    const float* X2 = (const float*)d_in[6];
    const float* X3 = (const float*)d_in[7];
    const float* X4 = (const float*)d_in[8];
    const float* X5 = (const float*)d_in[9];
    const float* W1  = (const float*)d_in[10];
    const float* V1  = (const float*)d_in[11];
    const float* b1  = (const float*)d_in[12];
    const float* W2  = (const float*)d_in[13];
    const float* V2  = (const float*)d_in[14];
    const float* b2  = (const float*)d_in[15];
    const float* Wlt = (const float*)d_in[16];
    const float* blt = (const float*)d_in[17];
    const float* Wl2 = (const float*)d_in[18];
    const float* bl2 = (const float*)d_in[19];
    const float* Wd  = (const float*)d_in[20];
    const float* bd  = (const float*)d_in[21];
    const float* Wg  = (const float*)d_in[22];
    const float* bg  = (const float*)d_in[23];

    char* ws = (char*)d_ws;
    int*   deg    = (int*)(ws + OFF_DEG);
    int*   cursor = (int*)(ws + OFF_CURSOR);
    float* dinv   = (float*)(ws + OFF_DINV);
    int*   rowptr = (int*)(ws + OFF_ROWPTR);
    int*   csrc   = (int*)(ws + OFF_CSRC);
    float* csrw   = (float*)(ws + OFF_CSRW);
    unsigned short* H1u = (unsigned short*)(ws + OFF_H1);
    float* Pbuf   = (float*)(ws + OFF_P);
    unsigned short* Yu = (unsigned short*)(ws + OFF_Y);
    unsigned short* H2u = (unsigned short*)(ws + OFF_H2);
    float* YV     = (float*)(ws + OFF_YV);
    float* Tbuf   = (float*)(ws + OFF_T);

    hipMemsetAsync(d_ws, 0, ZBYTES, stream);

    count_deg_kernel<<<1024, 256, 0, stream>>>(e0 + EE, e1 + EE, e2 + EE, e3 + EE, deg);
    scan_dinv_kernel<<<4, 256, 0, stream>>>(deg, rowptr, dinv);
    fill_csr_kernel<<<1024, 256, 0, stream>>>(e0, e0 + EE, e1, e1 + EE, e2, e2 + EE,
                                              e3, e3 + EE, rowptr, cursor, dinv, csrc, csrw);

    gemm48_mfma<<<dim3(512, 6), 256, 0, stream>>>(X0, X1, X2, X3, X4, X5,
                                                  W1, V1, b1, H1u, Yu);
    gemm48_lt<<<256, 512, 0, stream>>>(X5, Wlt, blt, Tbuf);
    spmm1_all<<<15360, 256, 0, stream>>>((const uint2*)H1u, (uint2*)Yu,
                                         rowptr, csrc, csrw);
    gemm2_all<<<dim3(512, 6), 256, 0, stream>>>(Yu, W2, V2, b2, H2u, YV);
    spmm2_all<<<6144, 256, 0, stream>>>((const uint2*)H2u, YV,
                                        rowptr, csrc, csrw, Pbuf);
    combine_kernel<<<512, 256, 0, stream>>>(Tbuf, Pbuf, Wl2, bl2, Wd, bd, Wg, bg,
                                            (float*)d_out);
}

// Round 13
// 226.091 us; speedup vs baseline: 8.9566x; 1.1261x over previous
//
#include <hip/hip_runtime.h>
#include <math.h>

// Problem dims
#define NN   2048      // nodes
#define BB   64        // batch
#define FF   48        // in features
#define EE   65536     // edges per graph
#define CC   7         // out channels
#define HH   20        // hidden

// ---- ws layout (bytes), ws_size = 256 MiB ----
#define OFF_DEG      0u
#define OFF_CURSOR   32768u
#define ZBYTES       65536u
#define OFF_DINV     65536u            // float[4][N]
#define OFF_ROWPTR   98304u            // int[4][N+1]
#define OFF_CSRC     131584u           // int[4][E]
#define OFF_CSRW     1180160u          // float[4][E]
#define OFF_H1       2228736u          // 6 x bf16[N][20][B] (u16) = 6 x 5.24MB
#define OFF_P        OFF_H1            // 6 x float[N][7][B], overlays H1 (dead at spmm2)
#define OFF_Y        65143296u         // 6 x bf16[N][20][B] (u16); init = xV+b, act in place
#define OFF_H2       128057856u        // 6 x bf16[N][8][B] (u16, padded to 8 ch) = 6 x 2MB
#define OFF_YV       153223680u        // 6 x float[N][7][B]
#define OFF_T        175243776u        // float[N][40][B] 21MB
// end = 196,215,296 B < 256 MiB

#define H1S  2621440u   // elements per branch in H1(u16) / Y(u16)
#define H2S  1048576u   // u16 elements per branch in H2 (padded)
#define YVS  917504u    // floats per branch in YV / P

typedef __attribute__((ext_vector_type(8))) short bf16x8;
typedef __attribute__((ext_vector_type(4))) float f32x4;
#define MFMA32 __builtin_amdgcn_mfma_f32_16x16x32_bf16

__device__ __forceinline__ unsigned short bf16_rne(float x) {
    unsigned u = __float_as_uint(x);
    u += 0x7fffu + ((u >> 16) & 1u);
    return (unsigned short)(u >> 16);
}
__device__ __forceinline__ float4 ubf4(uint2 u) {
    float4 r;
    r.x = __uint_as_float(u.x << 16);
    r.y = __uint_as_float(u.x & 0xffff0000u);
    r.z = __uint_as_float(u.y << 16);
    r.w = __uint_as_float(u.y & 0xffff0000u);
    return r;
}

// ---------------- CSR build ----------------
__global__ __launch_bounds__(256) void count_deg_kernel(
    const int* __restrict__ c0, const int* __restrict__ c1,
    const int* __restrict__ c2, const int* __restrict__ c3, int* __restrict__ deg)
{
    int idx = blockIdx.x * 256 + threadIdx.x;          // 4*E threads
    int g = idx >> 16, e = idx & 0xFFFF;
    const int* cp = g == 0 ? c0 : g == 1 ? c1 : g == 2 ? c2 : c3;
    atomicAdd(&deg[(g << 11) + cp[e]], 1);
}

__global__ __launch_bounds__(256) void scan_dinv_kernel(
    const int* __restrict__ deg, int* __restrict__ rowptr, float* __restrict__ dinv)
{
    int g = blockIdx.x, t = threadIdx.x;
    __shared__ int part[256];
    const int* d = deg + g * NN;
    int loc[8]; int s = 0;
#pragma unroll
    for (int j = 0; j < 8; ++j) { loc[j] = d[t * 8 + j]; s += loc[j]; }
    part[t] = s; __syncthreads();
    for (int off = 1; off < 256; off <<= 1) {
        int v = (t >= off) ? part[t - off] : 0;
        __syncthreads();
        part[t] += v;
        __syncthreads();
    }
    int run = (t > 0) ? part[t - 1] : 0;
    int* rp = rowptr + g * (NN + 1);
#pragma unroll
    for (int j = 0; j < 8; ++j) {
        int n = t * 8 + j;
        rp[n] = run; run += loc[j];
        dinv[g * NN + n] = loc[j] > 0 ? 1.0f / sqrtf((float)loc[j]) : 0.0f;
    }
    if (t == 255) rp[NN] = run;
}

__global__ __launch_bounds__(256) void fill_csr_kernel(
    const int* __restrict__ r0, const int* __restrict__ c0,
    const int* __restrict__ r1, const int* __restrict__ c1,
    const int* __restrict__ r2, const int* __restrict__ c2,
    const int* __restrict__ r3, const int* __restrict__ c3,
    const int* __restrict__ rowptr, int* __restrict__ cursor,
    const float* __restrict__ dinv, int* __restrict__ csrc, float* __restrict__ cw)
{
    int idx = blockIdx.x * 256 + threadIdx.x;
    int g = idx >> 16, e = idx & 0xFFFF;
    const int* rp = g == 0 ? r0 : g == 1 ? r1 : g == 2 ? r2 : r3;
    const int* cp = g == 0 ? c0 : g == 1 ? c1 : g == 2 ? c2 : c3;
    int r = rp[e], c = cp[e];
    int pos = atomicAdd(&cursor[(g << 11) + c], 1);
    int o = rowptr[g * (NN + 1) + c] + pos;
    csrc[(g << 16) + o] = r;
    cw[(g << 16) + o] = dinv[(g << 11) + r] * dinv[(g << 11) + c];
}

// ---------------- unified MFMA GEMM (7 branches) ----------------
// br<6: [M,48]@[48,20] x2 -> H1 bf16 + Y bf16.  br==6: [M,48]@[48,40] -> T f32.
// X staged in LDS [256 rows][48] padded to 52 (conflict-free both sides, r7).
// Block = 256 thr = 4 waves = 4 nodes; wave does its node's 4 batch-16 tiles.
// A frag: lane row=l&15, k = 32c + (l>>4)*8 + j; B frag: col=l&15, same k-map.
// C/D: col=lane&15, row=(lane>>4)*4+reg [m89-verified].
__global__ __launch_bounds__(256) void gemm48_mfma(
    const float* __restrict__ X0, const float* __restrict__ X1,
    const float* __restrict__ X2, const float* __restrict__ X3,
    const float* __restrict__ X4, const float* __restrict__ X5,
    const float* __restrict__ W1, const float* __restrict__ V1,
    const float* __restrict__ b1,
    const float* __restrict__ Wlt, const float* __restrict__ blt,
    unsigned short* __restrict__ H1u, unsigned short* __restrict__ Yu,
    float* __restrict__ T)
{
    int br = blockIdx.y;
    const float* X = br == 0 ? X0 : br == 1 ? X1 : br == 2 ? X2 :
                     br == 3 ? X3 : br == 4 ? X4 : X5;

    __shared__ float xs[256 * 52];   // 53248 B
    int t = threadIdx.x;
    const float4* Xv = reinterpret_cast<const float4*>(X) + (size_t)blockIdx.x * 3072;

    // coalesced stage: 3072 float4s
#pragma unroll
    for (int i = 0; i < 12; ++i) {
        int fl4 = i * 256 + t;
        float4 v = Xv[fl4];
        int r = fl4 / 12, fq = fl4 % 12;
        *reinterpret_cast<float4*>(&xs[r * 52 + fq * 4]) = v;
    }

    int w = t >> 6, lane = t & 63;
    int node = blockIdx.x * 4 + w;
    int col = lane & 15;
    int grp = lane >> 4;

    if (br < 6) {
        const float* Wa = W1 + br * 960;
        const float* Wb = V1 + br * 960;
        // B-frags: [chunk][ntile] for W and V
        bf16x8 bw[2][2], bv[2][2];
#pragma unroll
        for (int c = 0; c < 2; ++c)
#pragma unroll
            for (int nt = 0; nt < 2; ++nt) {
                int n = nt * 16 + col;
#pragma unroll
                for (int j = 0; j < 8; ++j) {
                    int k = c * 32 + grp * 8 + j;
                    float vw = 0.0f, vv = 0.0f;
                    if (n < 20 && k < 48) { vw = Wa[k * 20 + n]; vv = Wb[k * 20 + n]; }
                    bw[c][nt][j] = (short)bf16_rne(vw);
                    bv[c][nt][j] = (short)bf16_rne(vv);
                }
            }
        float bias0 = b1[br * 20 + col];
        float bias1 = col < 4 ? b1[br * 20 + 16 + col] : 0.0f;
        __syncthreads();

#pragma unroll
        for (int tb = 0; tb < 4; ++tb) {
            int b0 = tb * 16;
            int row = w * 64 + b0 + col;
            const float* xr = &xs[row * 52];

            bf16x8 a0;
            {
                float4 xa = *reinterpret_cast<const float4*>(xr + grp * 8);
                float4 xb = *reinterpret_cast<const float4*>(xr + grp * 8 + 4);
                a0[0] = (short)bf16_rne(xa.x); a0[1] = (short)bf16_rne(xa.y);
                a0[2] = (short)bf16_rne(xa.z); a0[3] = (short)bf16_rne(xa.w);
                a0[4] = (short)bf16_rne(xb.x); a0[5] = (short)bf16_rne(xb.y);
                a0[6] = (short)bf16_rne(xb.z); a0[7] = (short)bf16_rne(xb.w);
            }
            bf16x8 a1 = {0, 0, 0, 0, 0, 0, 0, 0};
            if (grp < 2) {
                float4 xc = *reinterpret_cast<const float4*>(xr + 32 + grp * 8);
                float4 xd = *reinterpret_cast<const float4*>(xr + 32 + grp * 8 + 4);
                a1[0] = (short)bf16_rne(xc.x); a1[1] = (short)bf16_rne(xc.y);
                a1[2] = (short)bf16_rne(xc.z); a1[3] = (short)bf16_rne(xc.w);
                a1[4] = (short)bf16_rne(xd.x); a1[5] = (short)bf16_rne(xd.y);
                a1[6] = (short)bf16_rne(xd.z); a1[7] = (short)bf16_rne(xd.w);
            }

            f32x4 aw0 = {0,0,0,0}, aw1 = {0,0,0,0}, av0 = {0,0,0,0}, av1 = {0,0,0,0};
            aw0 = MFMA32(a0, bw[0][0], aw0, 0, 0, 0);
            aw1 = MFMA32(a0, bw[0][1], aw1, 0, 0, 0);
            av0 = MFMA32(a0, bv[0][0], av0, 0, 0, 0);
            av1 = MFMA32(a0, bv[0][1], av1, 0, 0, 0);
            aw0 = MFMA32(a1, bw[1][0], aw0, 0, 0, 0);
            aw1 = MFMA32(a1, bw[1][1], aw1, 0, 0, 0);
            av0 = MFMA32(a1, bv[1][0], av0, 0, 0, 0);
            av1 = MFMA32(a1, bv[1][1], av1, 0, 0, 0);

            size_t base = (size_t)br * H1S + (size_t)node * 1280 + b0 + grp * 4;
            uint2 pk;
            pk.x = (unsigned)bf16_rne(aw0[0]) | ((unsigned)bf16_rne(aw0[1]) << 16);
            pk.y = (unsigned)bf16_rne(aw0[2]) | ((unsigned)bf16_rne(aw0[3]) << 16);
            *reinterpret_cast<uint2*>(H1u + base + (size_t)col * 64) = pk;
            pk.x = (unsigned)bf16_rne(av0[0] + bias0) | ((unsigned)bf16_rne(av0[1] + bias0) << 16);
            pk.y = (unsigned)bf16_rne(av0[2] + bias0) | ((unsigned)bf16_rne(av0[3] + bias0) << 16);
            *reinterpret_cast<uint2*>(Yu + base + (size_t)col * 64) = pk;
            if (col < 4) {
                int k2 = 16 + col;
                pk.x = (unsigned)bf16_rne(aw1[0]) | ((unsigned)bf16_rne(aw1[1]) << 16);
                pk.y = (unsigned)bf16_rne(aw1[2]) | ((unsigned)bf16_rne(aw1[3]) << 16);
                *reinterpret_cast<uint2*>(H1u + base + (size_t)k2 * 64) = pk;
                pk.x = (unsigned)bf16_rne(av1[0] + bias1) | ((unsigned)bf16_rne(av1[1] + bias1) << 16);
                pk.y = (unsigned)bf16_rne(av1[2] + bias1) | ((unsigned)bf16_rne(av1[3] + bias1) << 16);
                *reinterpret_cast<uint2*>(Yu + base + (size_t)k2 * 64) = pk;
            }
        }
    } else {
        // o_lt: [M,48]@[48,40] (N padded to 48 -> 3 ntiles), out T f32 + blt bias
        bf16x8 bw[2][3];
#pragma unroll
        for (int c = 0; c < 2; ++c)
#pragma unroll
            for (int nt = 0; nt < 3; ++nt) {
                int n = nt * 16 + col;
#pragma unroll
                for (int j = 0; j < 8; ++j) {
                    int k = c * 32 + grp * 8 + j;
                    float vw = 0.0f;
                    if (n < 40 && k < 48) vw = Wlt[k * 40 + n];
                    bw[c][nt][j] = (short)bf16_rne(vw);
                }
            }
        float bias[3];
#pragma unroll
        for (int nt = 0; nt < 3; ++nt) {
            int n = nt * 16 + col;
            bias[nt] = n < 40 ? blt[n] : 0.0f;
        }
        __syncthreads();

#pragma unroll
        for (int tb = 0; tb < 4; ++tb) {
            int b0 = tb * 16;
            int row = w * 64 + b0 + col;
            const float* xr = &xs[row * 52];

            bf16x8 a0;
            {
                float4 xa = *reinterpret_cast<const float4*>(xr + grp * 8);
                float4 xb = *reinterpret_cast<const float4*>(xr + grp * 8 + 4);
                a0[0] = (short)bf16_rne(xa.x); a0[1] = (short)bf16_rne(xa.y);
                a0[2] = (short)bf16_rne(xa.z); a0[3] = (short)bf16_rne(xa.w);
                a0[4] = (short)bf16_rne(xb.x); a0[5] = (short)bf16_rne(xb.y);
                a0[6] = (short)bf16_rne(xb.z); a0[7] = (short)bf16_rne(xb.w);
            }
            bf16x8 a1 = {0, 0, 0, 0, 0, 0, 0, 0};
            if (grp < 2) {
                float4 xc = *reinterpret_cast<const float4*>(xr + 32 + grp * 8);
                float4 xd = *reinterpret_cast<const float4*>(xr + 32 + grp * 8 + 4);
                a1[0] = (short)bf16_rne(xc.x); a1[1] = (short)bf16_rne(xc.y);
                a1[2] = (short)bf16_rne(xc.z); a1[3] = (short)bf16_rne(xc.w);
                a1[4] = (short)bf16_rne(xd.x); a1[5] = (short)bf16_rne(xd.y);
                a1[6] = (short)bf16_rne(xd.z); a1[7] = (short)bf16_rne(xd.w);
            }

            f32x4 ac[3] = {{0,0,0,0},{0,0,0,0},{0,0,0,0}};
#pragma unroll
            for (int nt = 0; nt < 3; ++nt) {
                ac[nt] = MFMA32(a0, bw[0][nt], ac[nt], 0, 0, 0);
                ac[nt] = MFMA32(a1, bw[1][nt], ac[nt], 0, 0, 0);
            }

            size_t base = (size_t)node * 2560 + b0 + grp * 4;
#pragma unroll
            for (int nt = 0; nt < 3; ++nt) {
                int n = nt * 16 + col;
                if (n < 40) {
                    float4 v = { ac[nt][0] + bias[nt], ac[nt][1] + bias[nt],
                                 ac[nt][2] + bias[nt], ac[nt][3] + bias[nt] };
                    *reinterpret_cast<float4*>(&T[base + (size_t)n * 64]) = v;
                }
            }
        }
    }
}

__device__ __forceinline__ void fma4(float4& a, float w, const float4 v) {
    a.x += w * v.x; a.y += w * v.y; a.z += w * v.z; a.w += w * v.w;
}
__device__ __forceinline__ float gelu_elu(float v) {
    float g = 0.5f * v * (1.0f + erff(v * 0.70710678118654752f));   // exact GELU
    return g > 0.0f ? g : expm1f(g);                                 // ELU
}

// ---------------- batched SpMM1 + GELU + ELU, bf16 gather, in-place on bf16 Y ----------------
// XCD-pinned slices; scalarized CSR; 8-deep gather of uint2 (4 bf16).
__global__ __launch_bounds__(256) void spmm1_all(
    const uint2* __restrict__ H1u, uint2* __restrict__ Y,
    const int* __restrict__ rowptr, const int* __restrict__ csrc, const float* __restrict__ csrw)
{
    int bid = blockIdx.x;
    int w0 = (bid & 7) * 1920 + (bid >> 3);   // 0..15359
    int sl = w0 >> 9;                          // 0..29
    int ng = w0 & 511;
    int br = sl / 5, q = sl - br * 5;

    int gg = br == 1 ? 1 : br == 2 ? 2 : br == 5 ? 3 : 0;
    const int*   rp  = rowptr + gg * (NN + 1);
    const int*   src = csrc + (size_t)gg * EE;
    const float* wts = csrw + (size_t)gg * EE;
    const uint2* h = H1u + (size_t)br * (H1S / 4);   // 320 uint2 per node-row
    uint2*       y = Y + (size_t)br * (H1S / 4);     // 320 uint2 per node-row

    int wv = __builtin_amdgcn_readfirstlane(threadIdx.x >> 6);
    int lane = threadIdx.x & 63;
    int n = ng * 4 + wv;                       // wave-uniform -> scalar CSR loads
    int off = q * 64 + lane;
    int s0 = rp[n], s1 = rp[n + 1];

    float4 a0 = {0,0,0,0}, a1 = {0,0,0,0}, a2 = {0,0,0,0}, a3 = {0,0,0,0};
    int e = s0;
    for (; e + 8 <= s1; e += 8) {
        int   iA = src[e],   iB = src[e+1], iC = src[e+2], iD = src[e+3];
        int   iE = src[e+4], iF = src[e+5], iG = src[e+6], iH = src[e+7];
        float wA = wts[e],   wB = wts[e+1], wC = wts[e+2], wD = wts[e+3];
        float wE = wts[e+4], wF = wts[e+5], wG = wts[e+6], wH = wts[e+7];
        uint2 u0 = h[iA * 320 + off];
        uint2 u1 = h[iB * 320 + off];
        uint2 u2 = h[iC * 320 + off];
        uint2 u3 = h[iD * 320 + off];
        uint2 u4 = h[iE * 320 + off];
        uint2 u5 = h[iF * 320 + off];
        uint2 u6 = h[iG * 320 + off];
        uint2 u7 = h[iH * 320 + off];
        fma4(a0, wA, ubf4(u0)); fma4(a1, wB, ubf4(u1));
        fma4(a2, wC, ubf4(u2)); fma4(a3, wD, ubf4(u3));
        fma4(a0, wE, ubf4(u4)); fma4(a1, wF, ubf4(u5));
        fma4(a2, wG, ubf4(u6)); fma4(a3, wH, ubf4(u7));
    }
    for (; e + 2 <= s1; e += 2) {
        uint2 u0 = h[src[e] * 320 + off];
        uint2 u1 = h[src[e+1] * 320 + off];
        fma4(a0, wts[e], ubf4(u0)); fma4(a1, wts[e+1], ubf4(u1));
    }
    if (e < s1) fma4(a0, wts[e], ubf4(h[src[e] * 320 + off]));
    a0.x += a1.x + a2.x + a3.x;
    a0.y += a1.y + a2.y + a3.y;
    a0.z += a1.z + a2.z + a3.z;
    a0.w += a1.w + a2.w + a3.w;

    size_t b0 = (size_t)n * 320 + off;
    float4 xv = ubf4(y[b0]);
    float4 r;
    r.x = gelu_elu(a0.x + xv.x);
    r.y = gelu_elu(a0.y + xv.y);
    r.z = gelu_elu(a0.z + xv.z);
    r.w = gelu_elu(a0.w + xv.w);
    uint2 pk;
    pk.x = (unsigned)bf16_rne(r.x) | ((unsigned)bf16_rne(r.y) << 16);
    pk.y = (unsigned)bf16_rne(r.z) | ((unsigned)bf16_rne(r.w) << 16);
    y[b0] = pk;
}

// ---------------- batched dual GEMM2: [M,20]@[20,7] x2; Y bf16 in, H2 bf16 out ----------------
__global__ __launch_bounds__(256) void gemm2_all(
    const unsigned short* __restrict__ Yu, const float* __restrict__ W2,
    const float* __restrict__ V2, const float* __restrict__ b2,
    unsigned short* __restrict__ H2u, float* __restrict__ YV)
{
    int br = blockIdx.y;
    const unsigned short* y = Yu + (size_t)br * H1S;
    unsigned short* h2 = H2u + (size_t)br * H2S;
    float* yv = YV + (size_t)br * YVS;
    __shared__ float w2s[140], v2s[140], b2s[7];
    int t = threadIdx.x;
    if (t < 140) { w2s[t] = W2[br * 140 + t]; v2s[t] = V2[br * 140 + t]; }
    if (t < 7) b2s[t] = b2[br * 7 + t];
    __syncthreads();
    int wv = __builtin_amdgcn_readfirstlane(t >> 6), b = t & 63;
    int n = blockIdx.x * 4 + wv;
    size_t yb = (size_t)n * 1280 + b;
    float yr[20];
#pragma unroll
    for (int k = 0; k < 20; ++k)
        yr[k] = __uint_as_float((unsigned)y[yb + (size_t)k * 64] << 16);
    float a[7] = {}, v[7] = {};
#pragma unroll
    for (int k = 0; k < 20; ++k) {
        float yk = yr[k];
#pragma unroll
        for (int c = 0; c < 7; ++c) {
            a[c] += yk * w2s[k * 7 + c];
            v[c] += yk * v2s[k * 7 + c];
        }
    }
    size_t hb = (size_t)n * 512 + b;
#pragma unroll
    for (int c = 0; c < 7; ++c) h2[hb + (size_t)c * 64] = bf16_rne(a[c]);
    h2[hb + 7 * 64] = 0;                          // padding channel
    size_t vb = (size_t)n * 448 + b;
#pragma unroll
    for (int c = 0; c < 7; ++c) yv[vb + (size_t)c * 64] = v[c] + b2s[c];
}

// ---------------- batched SpMM2 + ReLU + softmax(B) -> per-branch P ----------------
// XCD-pinned; scalarized CSR; 8-deep bf16 gather. Row = [8 ch][64 b] u16 = 128 uint2.
__global__ __launch_bounds__(256) void spmm2_all(
    const uint2* __restrict__ H2u, const float* __restrict__ YV,
    const int* __restrict__ rowptr, const int* __restrict__ csrc, const float* __restrict__ csrw,
    float* __restrict__ P)
{
    int bid = blockIdx.x;
    int w0 = (bid & 7) * 768 + (bid >> 3);    // 0..6143
    int sl = w0 >> 9;                          // 0..11
    int ng = w0 & 511;
    int br = sl >> 1, hh = sl & 1;

    int gg = br == 1 ? 1 : br == 2 ? 2 : br == 5 ? 3 : 0;
    const int*   rp  = rowptr + gg * (NN + 1);
    const int*   src = csrc + (size_t)gg * EE;
    const float* wts = csrw + (size_t)gg * EE;
    const uint2* h2 = H2u + (size_t)br * (H2S / 4);   // 128 uint2 per node-row
    const float* yv = YV + (size_t)br * YVS;
    float* p = P + (size_t)br * YVS;

    int wv = __builtin_amdgcn_readfirstlane(threadIdx.x >> 6);
    int lane = threadIdx.x & 63;
    int n = ng * 4 + wv;
    int s = hh * 64 + lane;          // uint2 slot in the 128-slot row
    int c = s >> 4;                  // 0..7 (7 = padding)
    int bq = lane & 15;              // b quad
    int s0 = rp[n], s1 = rp[n + 1];

    float4 a0 = {0,0,0,0}, a1 = {0,0,0,0}, a2 = {0,0,0,0}, a3 = {0,0,0,0};
    int e = s0;
    for (; e + 8 <= s1; e += 8) {
        int   iA = src[e],   iB = src[e+1], iC = src[e+2], iD = src[e+3];
        int   iE = src[e+4], iF = src[e+5], iG = src[e+6], iH = src[e+7];
        float wA = wts[e],   wB = wts[e+1], wC = wts[e+2], wD = wts[e+3];
        float wE = wts[e+4], wF = wts[e+5], wG = wts[e+6], wH = wts[e+7];
        uint2 u0 = h2[iA * 128 + s];
        uint2 u1 = h2[iB * 128 + s];
        uint2 u2 = h2[iC * 128 + s];
        uint2 u3 = h2[iD * 128 + s];
        uint2 u4 = h2[iE * 128 + s];
        uint2 u5 = h2[iF * 128 + s];
        uint2 u6 = h2[iG * 128 + s];
        uint2 u7 = h2[iH * 128 + s];
        fma4(a0, wA, ubf4(u0)); fma4(a1, wB, ubf4(u1));
        fma4(a2, wC, ubf4(u2)); fma4(a3, wD, ubf4(u3));
        fma4(a0, wE, ubf4(u4)); fma4(a1, wF, ubf4(u5));
        fma4(a2, wG, ubf4(u6)); fma4(a3, wH, ubf4(u7));
    }
    for (; e < s1; ++e) fma4(a0, wts[e], ubf4(h2[src[e] * 128 + s]));
    a0.x += a1.x + a2.x + a3.x;
    a0.y += a1.y + a2.y + a3.y;
    a0.z += a1.z + a2.z + a3.z;
    a0.w += a1.w + a2.w + a3.w;

    float4 z = {0,0,0,0};
    if (c < 7) {
        float4 yvv = *reinterpret_cast<const float4*>(&yv[(size_t)n * 448 + c * 64 + bq * 4]);
        z.x = fmaxf(a0.x + yvv.x, 0.0f);
        z.y = fmaxf(a0.y + yvv.y, 0.0f);
        z.z = fmaxf(a0.z + yvv.z, 0.0f);
        z.w = fmaxf(a0.w + yvv.w, 0.0f);
    }
    float m = fmaxf(fmaxf(z.x, z.y), fmaxf(z.z, z.w));
#pragma unroll
    for (int o = 8; o > 0; o >>= 1) m = fmaxf(m, __shfl_xor(m, o, 64));
    float4 pz;
    pz.x = expf(z.x - m); pz.y = expf(z.y - m);
    pz.z = expf(z.z - m); pz.w = expf(z.w - m);
    float sm = pz.x + pz.y + pz.z + pz.w;
#pragma unroll
    for (int o = 8; o > 0; o >>= 1) sm += __shfl_xor(sm, o, 64);
    float inv = 1.0f / sm;
    if (c < 7) {
        float4 r = { pz.x * inv, pz.y * inv, pz.z * inv, pz.w * inv };
        *reinterpret_cast<float4*>(&p[(size_t)n * 448 + c * 64 + bq * 4]) = r;
    }
}

// ---------------- wave softmax over 64 lanes (batch axis) ----------------
__device__ __forceinline__ void wave_softmax7(float* z)
{
#pragma unroll
    for (int c = 0; c < 7; ++c) {
        float m = z[c];
#pragma unroll
        for (int o = 32; o > 0; o >>= 1) m = fmaxf(m, __shfl_xor(m, o, 64));
        float p = expf(z[c] - m);
        float s = p;
#pragma unroll
        for (int o = 32; o > 0; o >>= 1) s += __shfl_xor(s, o, 64);
        z[c] = p / s;
    }
}

// ---------------- final: o_lt tail, dense+gnn heads, output [N][C][B] ----------------
__global__ __launch_bounds__(256) void combine_kernel(
    const float* __restrict__ T, const float* __restrict__ P,
    const float* __restrict__ Wl2, const float* __restrict__ bl2,
    const float* __restrict__ Wd, const float* __restrict__ bd,
    const float* __restrict__ Wg, const float* __restrict__ bg,
    float* __restrict__ out)
{
    __shared__ float wl2s[280], bl2s[7], wds[49], bds[7], wgs[49], bgs[7];
    int t = threadIdx.x;
    for (int i = t; i < 280; i += 256) wl2s[i] = Wl2[i];
    if (t < 49) { wds[t] = Wd[t]; wgs[t] = Wg[t]; }
    if (t < 7) { bl2s[t] = bl2[t]; bds[t] = bd[t]; bgs[t] = bg[t]; }
    __syncthreads();

    int wv = t >> 6, b = t & 63;
    int n = blockIdx.x * 4 + wv;
    size_t rbase = (size_t)n * 2560 + b;   // T is [n][40][b]
    float tr[40];
#pragma unroll
    for (int j = 0; j < 40; ++j) tr[j] = T[rbase + (size_t)j * 64];

    float u[7];
#pragma unroll
    for (int c = 0; c < 7; ++c) u[c] = bl2s[c];
    for (int j = 0; j < 40; ++j) {
        float tv = tr[j];
#pragma unroll
        for (int c = 0; c < 7; ++c) u[c] += tv * wl2s[j * 7 + c];
    }
    wave_softmax7(u);   // o_lt

    size_t sbase = (size_t)n * 448 + b;
    float sd[7], sg[7];
#pragma unroll
    for (int c = 0; c < 7; ++c) {
        size_t o = sbase + (size_t)c * 64;
        sg[c] = P[o] + P[YVS + o] + P[2 * YVS + o] + P[3 * YVS + o] + P[4 * YVS + o];
        sd[c] = 2.0f * P[5 * YVS + o] + 2.0f * u[c];
    }
    float dv[7];
#pragma unroll
    for (int c = 0; c < 7; ++c) dv[c] = bds[c];
#pragma unroll
    for (int c2 = 0; c2 < 7; ++c2) {
        float s = sd[c2];
#pragma unroll
        for (int c = 0; c < 7; ++c) dv[c] += s * wds[c2 * 7 + c];
    }
    wave_softmax7(dv);  // out_dense

    float gv[7];
#pragma unroll
    for (int c = 0; c < 7; ++c) gv[c] = bgs[c];
#pragma unroll
    for (int c2 = 0; c2 < 7; ++c2) {
        float s = sg[c2];
#pragma unroll
        for (int c = 0; c < 7; ++c) gv[c] += s * wgs[c2 * 7 + c];
    }
    wave_softmax7(gv);  // out_gnn

    size_t ob = (size_t)n * 448 + b;
#pragma unroll
    for (int c = 0; c < 7; ++c) out[ob + (size_t)c * 64] = dv[c] + gv[c];
}

// ---------------- host ----------------
extern "C" void kernel_launch(void* const* d_in, const int* in_sizes, int n_in,
                              void* d_out, int out_size, void* d_ws, size_t ws_size,
                              hipStream_t stream)
{
    (void)in_sizes; (void)n_in; (void)out_size; (void)ws_size;
    const int* e0 = (const int*)d_in[0];
    const int* e1 = (const int*)d_in[1];
    const int* e2 = (const int*)d_in[2];
    const int* e3 = (const int*)d_in[3];
    const float* X0 = (const float*)d_in[4];
    const float* X1 = (const float*)d_in[5];
    const float* X2 = (const float*)d_in[6];
    const float* X3 = (const float*)d_in[7];
    const float* X4 = (const float*)d_in[8];
    const float* X5 = (const float*)d_in[9];
    const float* W1  = (const float*)d_in[10];
    const float* V1  = (const float*)d_in[11];
    const float* b1  = (const float*)d_in[12];
    const float* W2  = (const float*)d_in[13];
    const float* V2  = (const float*)d_in[14];
    const float* b2  = (const float*)d_in[15];
    const float* Wlt = (const float*)d_in[16];
    const float* blt = (const float*)d_in[17];
    const float* Wl2 = (const float*)d_in[18];
    const float* bl2 = (const float*)d_in[19];
    const float* Wd  = (const float*)d_in[20];
    const float* bd  = (const float*)d_in[21];
    const float* Wg  = (const float*)d_in[22];
    const float* bg  = (const float*)d_in[23];

    char* ws = (char*)d_ws;
    int*   deg    = (int*)(ws + OFF_DEG);
    int*   cursor = (int*)(ws + OFF_CURSOR);
    float* dinv   = (float*)(ws + OFF_DINV);
    int*   rowptr = (int*)(ws + OFF_ROWPTR);
    int*   csrc   = (int*)(ws + OFF_CSRC);
    float* csrw   = (float*)(ws + OFF_CSRW);
    unsigned short* H1u = (unsigned short*)(ws + OFF_H1);
    float* Pbuf   = (float*)(ws + OFF_P);
    unsigned short* Yu = (unsigned short*)(ws + OFF_Y);
    unsigned short* H2u = (unsigned short*)(ws + OFF_H2);
    float* YV     = (float*)(ws + OFF_YV);
    float* Tbuf   = (float*)(ws + OFF_T);

    hipMemsetAsync(d_ws, 0, ZBYTES, stream);

    count_deg_kernel<<<1024, 256, 0, stream>>>(e0 + EE, e1 + EE, e2 + EE, e3 + EE, deg);
    scan_dinv_kernel<<<4, 256, 0, stream>>>(deg, rowptr, dinv);
    fill_csr_kernel<<<1024, 256, 0, stream>>>(e0, e0 + EE, e1, e1 + EE, e2, e2 + EE,
                                              e3, e3 + EE, rowptr, cursor, dinv, csrc, csrw);

    gemm48_mfma<<<dim3(512, 7), 256, 0, stream>>>(X0, X1, X2, X3, X4, X5,
                                                  W1, V1, b1, Wlt, blt, H1u, Yu, Tbuf);
    spmm1_all<<<15360, 256, 0, stream>>>((const uint2*)H1u, (uint2*)Yu,
                                         rowptr, csrc, csrw);
    gemm2_all<<<dim3(512, 6), 256, 0, stream>>>(Yu, W2, V2, b2, H2u, YV);
    spmm2_all<<<6144, 256, 0, stream>>>((const uint2*)H2u, YV,
                                        rowptr, csrc, csrw, Pbuf);
    combine_kernel<<<512, 256, 0, stream>>>(Tbuf, Pbuf, Wl2, bl2, Wd, bd, Wg, bg,
                                            (float*)d_out);
}